// Round 2
// baseline (6477.016 us; speedup 1.0000x reference)
//
#include <hip/hip_runtime.h>

#define NN 200000
#define NE 400000
#define NG 8192
#define HD 128
#define H2 256
#define ND 80
#define NC 500

// ------------------------------ zero helper ----------------------------------
__global__ void k_zero(float* p, int n) {
    int i = blockIdx.x * 256 + threadIdx.x;
    if (i < n) p[i] = 0.f;
}

// ---------------- node encoder: h = x @ node_w + node_b ; agg = 0 -------------
__global__ __launch_bounds__(256) void k_node_encode(
    const float* __restrict__ x, const float* __restrict__ w,
    const float* __restrict__ b, float* __restrict__ h, float* __restrict__ agg)
{
    __shared__ float ws[ND][HD];   // 40 KB
    __shared__ float xs[32][ND];   // 10 KB
    const int tid = threadIdx.x;
    for (int i = tid; i < ND * HD; i += 256) ws[i >> 7][i & 127] = w[i];
    const int row0 = blockIdx.x * 32;
    for (int i = tid; i < 32 * ND; i += 256) {
        int r = i / ND, c = i % ND;
        xs[r][c] = x[(size_t)(row0 + r) * ND + c];
    }
    __syncthreads();
    const int col = tid & 127, rs = tid >> 7;
    const float bias = b[col];
    for (int it = 0; it < 16; ++it) {
        int rl = it * 2 + rs;
        float acc = bias;
        #pragma unroll
        for (int k = 0; k < ND; ++k) acc += xs[rl][k] * ws[k][col];
        size_t gi = (size_t)(row0 + rl) * HD + col;
        h[gi] = acc;
        agg[gi] = 0.f;
    }
}

// ------- message + aggregate: agg[dst] += relu(h[src] + e_attr@ew + eb) ------
__global__ __launch_bounds__(256) void k_msg_agg(
    const float* __restrict__ h, const int* __restrict__ ei,
    const float* __restrict__ eattr, const float* __restrict__ ew,
    const float* __restrict__ eb, float* __restrict__ agg)
{
    __shared__ float ews[6][HD];
    __shared__ float ebs[HD];
    const int tid = threadIdx.x;
    for (int i = tid; i < 6 * HD; i += 256) ews[i >> 7][i & 127] = ew[i];
    if (tid < HD) ebs[tid] = eb[tid];
    __syncthreads();
    const int col = tid & 127, es = tid >> 7;
    const int e0 = blockIdx.x * 32;
    for (int it = 0; it < 16; ++it) {
        int e = e0 + it * 2 + es;
        int src = ei[e], dst = ei[NE + e];
        float a0 = eattr[e * 6 + 0], a1 = eattr[e * 6 + 1], a2 = eattr[e * 6 + 2];
        float a3 = eattr[e * 6 + 3], a4 = eattr[e * 6 + 4], a5 = eattr[e * 6 + 5];
        float m = h[(size_t)src * HD + col] + ebs[col]
                + a0 * ews[0][col] + a1 * ews[1][col] + a2 * ews[2][col]
                + a3 * ews[3][col] + a4 * ews[4][col] + a5 * ews[5][col];
        m = fmaxf(m, 0.f);
        atomicAdd(&agg[(size_t)dst * HD + col], m);
    }
}

// ---- Z-stats: colz[c] += sum_r Z[r][c];  M[i][j] += sum_r Z[r][i]*Z[r][j] ----
// Z = h + agg, tile of 128 rows per block.
__global__ __launch_bounds__(256) void k_zstats(
    const float* __restrict__ h, const float* __restrict__ agg,
    float* __restrict__ M, float* __restrict__ colz)
{
    __shared__ float zs[128][HD];  // 64 KB
    const int tid = threadIdx.x;
    const int r0 = blockIdx.x * 128;
    for (int i = 0; i < 16; ++i) {
        int fidx = tid + i * 256;          // float4 index, 4096 total
        int row = fidx >> 5, c4 = fidx & 31;
        float4 v = make_float4(0.f, 0.f, 0.f, 0.f);
        if (r0 + row < NN) {
            size_t gi = (size_t)(r0 + row) * HD + c4 * 4;
            float4 hv = *(const float4*)(h + gi);
            float4 av = *(const float4*)(agg + gi);
            v = make_float4(hv.x + av.x, hv.y + av.y, hv.z + av.z, hv.w + av.w);
        }
        *(float4*)(&zs[row][c4 * 4]) = v;
    }
    __syncthreads();
    if (tid < HD) {
        float s = 0.f;
        for (int r = 0; r < 128; ++r) s += zs[r][tid];
        atomicAdd(&colz[tid], s);
    }
    const int i0 = (tid >> 4) * 8, j0 = (tid & 15) * 8;
    float acc[8][8];
    #pragma unroll
    for (int a = 0; a < 8; ++a)
        #pragma unroll
        for (int c = 0; c < 8; ++c) acc[a][c] = 0.f;
    for (int r = 0; r < 128; ++r) {
        float4 zi0 = *(const float4*)(&zs[r][i0]);
        float4 zi1 = *(const float4*)(&zs[r][i0 + 4]);
        float4 zj0 = *(const float4*)(&zs[r][j0]);
        float4 zj1 = *(const float4*)(&zs[r][j0 + 4]);
        float zi[8] = {zi0.x, zi0.y, zi0.z, zi0.w, zi1.x, zi1.y, zi1.z, zi1.w};
        float zj[8] = {zj0.x, zj0.y, zj0.z, zj0.w, zj1.x, zj1.y, zj1.z, zj1.w};
        #pragma unroll
        for (int a = 0; a < 8; ++a)
            #pragma unroll
            for (int c = 0; c < 8; ++c) acc[a][c] += zi[a] * zj[c];
    }
    #pragma unroll
    for (int a = 0; a < 8; ++a)
        #pragma unroll
        for (int c = 0; c < 8; ++c)
            atomicAdd(&M[(i0 + a) * HD + j0 + c], acc[a][c]);
}

// -- BN1 prep from sufficient stats: var(Z@wc) = wc'M wc/N - (colz.wc/N)^2 ----
__global__ __launch_bounds__(128) void k_bnprep1(
    const float* __restrict__ M, const float* __restrict__ colz,
    const float* __restrict__ w1p, const float* __restrict__ b1p,
    const float* __restrict__ g, const float* __restrict__ b,
    float* __restrict__ scale, float* __restrict__ shift)
{
    __shared__ float wcs[128];
    __shared__ float red[128];
    __shared__ float red2[128];
    const int c = blockIdx.x;      // 0..255 output column
    const int j = threadIdx.x;     // 0..127
    float wc = w1p[j * H2 + c];
    wcs[j] = wc;
    __syncthreads();
    float inner = 0.f;
    for (int k = 0; k < 128; ++k) inner += M[j * HD + k] * wcs[k];
    red[j] = wc * inner;
    red2[j] = colz[j] * wc;
    __syncthreads();
    for (int s = 64; s > 0; s >>= 1) {
        if (j < s) { red[j] += red[j + s]; red2[j] += red2[j + s]; }
        __syncthreads();
    }
    if (j == 0) {
        const float invn = 1.f / NN;
        float q = red[0] * invn;
        float d = red2[0] * invn;
        float var = q - d * d;
        float mean = d + b1p[c];
        float sc = g[c] * rsqrtf(var + 1e-5f);
        scale[c] = sc;
        shift[c] = b[c] - mean * sc;
    }
}

// ---- fused conv: u = relu(bn1(Z@W1+b1)) @ W2 + b2 ; accumulate u col stats --
// u may alias agg (each block reads then writes only its own 16 rows).
__global__ __launch_bounds__(128) void k_fused(
    const float* __restrict__ h, const float* agg,
    const float* __restrict__ w1p, const float* __restrict__ b1p,
    const float* __restrict__ scale1, const float* __restrict__ shift1,
    const float* __restrict__ w2p, const float* __restrict__ b2p,
    float* u, float* __restrict__ uslotS, float* __restrict__ uslotSS)
{
    __shared__ float zs[16][HD];    // 8 KB
    __shared__ float ys[16][H2];    // 16 KB
    __shared__ float sred[2][HD];   // 1 KB
    __shared__ float ssred[2][HD];  // 1 KB
    const int tid = threadIdx.x;
    const int row0 = blockIdx.x * 16;
    for (int i = tid; i < 16 * HD; i += 128) {
        size_t gi = (size_t)row0 * HD + i;
        zs[i >> 7][i & 127] = h[gi] + agg[gi];
    }
    __syncthreads();
    // phase A: t = zs @ W1 (cols c0=tid, c1=tid+128), 16-row accumulators
    const int c0 = tid, c1 = tid + 128;
    float a0[16], a1[16];
    #pragma unroll
    for (int r = 0; r < 16; ++r) { a0[r] = 0.f; a1[r] = 0.f; }
    for (int kk = 0; kk < 32; ++kk) {
        float w00 = w1p[(kk * 4 + 0) * H2 + c0];
        float w01 = w1p[(kk * 4 + 1) * H2 + c0];
        float w02 = w1p[(kk * 4 + 2) * H2 + c0];
        float w03 = w1p[(kk * 4 + 3) * H2 + c0];
        float w10 = w1p[(kk * 4 + 0) * H2 + c1];
        float w11 = w1p[(kk * 4 + 1) * H2 + c1];
        float w12 = w1p[(kk * 4 + 2) * H2 + c1];
        float w13 = w1p[(kk * 4 + 3) * H2 + c1];
        #pragma unroll
        for (int r = 0; r < 16; ++r) {
            float4 z4 = *(const float4*)(&zs[r][kk * 4]);
            a0[r] += z4.x * w00; a0[r] += z4.y * w01;
            a0[r] += z4.z * w02; a0[r] += z4.w * w03;
            a1[r] += z4.x * w10; a1[r] += z4.y * w11;
            a1[r] += z4.z * w12; a1[r] += z4.w * w13;
        }
    }
    const float sc0 = scale1[c0], sh0 = shift1[c0];
    const float sc1 = scale1[c1], sh1 = shift1[c1];
    const float tb0 = b1p[c0], tb1 = b1p[c1];
    #pragma unroll
    for (int r = 0; r < 16; ++r) {
        ys[r][c0] = fmaxf((a0[r] + tb0) * sc0 + sh0, 0.f);
        ys[r][c1] = fmaxf((a1[r] + tb1) * sc1 + sh1, 0.f);
    }
    __syncthreads();
    // phase B: u = ys @ W2 (cols cp, cp+64; rows rg*8..rg*8+7)
    const int cp = tid & 63, rg = tid >> 6;
    float u0[8], u1[8];
    #pragma unroll
    for (int r = 0; r < 8; ++r) { u0[r] = 0.f; u1[r] = 0.f; }
    for (int kk = 0; kk < 64; ++kk) {
        float w00 = w2p[(kk * 4 + 0) * HD + cp];
        float w01 = w2p[(kk * 4 + 1) * HD + cp];
        float w02 = w2p[(kk * 4 + 2) * HD + cp];
        float w03 = w2p[(kk * 4 + 3) * HD + cp];
        float w10 = w2p[(kk * 4 + 0) * HD + cp + 64];
        float w11 = w2p[(kk * 4 + 1) * HD + cp + 64];
        float w12 = w2p[(kk * 4 + 2) * HD + cp + 64];
        float w13 = w2p[(kk * 4 + 3) * HD + cp + 64];
        #pragma unroll
        for (int r = 0; r < 8; ++r) {
            float4 z4 = *(const float4*)(&ys[rg * 8 + r][kk * 4]);
            u0[r] += z4.x * w00; u0[r] += z4.y * w01;
            u0[r] += z4.z * w02; u0[r] += z4.w * w03;
            u1[r] += z4.x * w10; u1[r] += z4.y * w11;
            u1[r] += z4.z * w12; u1[r] += z4.w * w13;
        }
    }
    const float ub0 = b2p[cp], ub1 = b2p[cp + 64];
    float s0 = 0.f, ss0 = 0.f, s1 = 0.f, ss1 = 0.f;
    #pragma unroll
    for (int r = 0; r < 8; ++r) {
        int row = row0 + rg * 8 + r;
        float v0 = u0[r] + ub0;
        float v1 = u1[r] + ub1;
        u[(size_t)row * HD + cp]      = v0;
        u[(size_t)row * HD + cp + 64] = v1;
        s0 += v0; ss0 += v0 * v0;
        s1 += v1; ss1 += v1 * v1;
    }
    sred[rg][cp] = s0;       ssred[rg][cp] = ss0;
    sred[rg][cp + 64] = s1;  ssred[rg][cp + 64] = ss1;
    __syncthreads();
    if (tid < HD) {
        int slot = blockIdx.x & 63;
        atomicAdd(&uslotS[slot * HD + tid],  sred[0][tid] + sred[1][tid]);
        atomicAdd(&uslotSS[slot * HD + tid], ssred[0][tid] + ssred[1][tid]);
    }
}

// ------------- BN2 prep: reduce 64 slots, emit scale/shift, zero slots -------
__global__ __launch_bounds__(128) void k_bnprep2(
    float* __restrict__ uslotS, float* __restrict__ uslotSS,
    const float* __restrict__ g, const float* __restrict__ b,
    float* __restrict__ scale, float* __restrict__ shift)
{
    const int c = threadIdx.x;   // 0..127
    float s = 0.f, ss = 0.f;
    for (int k = 0; k < 64; ++k) {
        s  += uslotS[k * HD + c];
        ss += uslotSS[k * HD + c];
        uslotS[k * HD + c] = 0.f;
        uslotSS[k * HD + c] = 0.f;
    }
    const float invn = 1.f / NN;
    float mean = s * invn;
    float var = ss * invn - mean * mean;
    float sc = g[c] * rsqrtf(var + 1e-5f);
    scale[c] = sc;
    shift[c] = b[c] - mean * sc;
}

// --------- normalize+relu: h = relu(u*scale+shift); zero u (=agg) ------------
__global__ __launch_bounds__(256) void k_norm(
    const float* __restrict__ scale, const float* __restrict__ shift,
    float* __restrict__ h, float* uio)
{
    int idx = blockIdx.x * 256 + threadIdx.x;   // float4 index
    float4 v = ((const float4*)uio)[idx];
    int c = (idx * 4) & 127;
    v.x = fmaxf(v.x * scale[c + 0] + shift[c + 0], 0.f);
    v.y = fmaxf(v.y * scale[c + 1] + shift[c + 1], 0.f);
    v.z = fmaxf(v.z * scale[c + 2] + shift[c + 2], 0.f);
    v.w = fmaxf(v.w * scale[c + 3] + shift[c + 3], 0.f);
    ((float4*)h)[idx] = v;
    ((float4*)uio)[idx] = make_float4(0.f, 0.f, 0.f, 0.f);
}

// -------- pool: per-graph mean & max over sorted batch (binary search) --------
__global__ __launch_bounds__(128) void k_pool(
    const float* __restrict__ h, const int* __restrict__ batch,
    float* __restrict__ pmean, float* __restrict__ pmax)
{
    const int g = blockIdx.x;
    const int tid = threadIdx.x;
    int lo = 0, hi = NN;
    while (lo < hi) { int mid = (lo + hi) >> 1; if (batch[mid] < g) lo = mid + 1; else hi = mid; }
    const int start = lo;
    hi = NN;
    while (lo < hi) { int mid = (lo + hi) >> 1; if (batch[mid] < g + 1) lo = mid + 1; else hi = mid; }
    const int end = lo;
    float s = 0.f, m = 0.f;
    for (int i = start; i < end; ++i) {
        float v = h[(size_t)i * HD + tid];
        s += v; m = fmaxf(m, v);
    }
    float cnt = (float)(end - start);
    pmean[g * HD + tid] = s / fmaxf(cnt, 1.f);
    pmax[g * HD + tid] = m;   // h >= 0 so 0-init matches reference's isfinite fixup
}

// ------------- classifier GEMM1: z1 = relu([mean||max] @ W + b) ---------------
__global__ __launch_bounds__(128) void k_cls1(
    const float* __restrict__ pmean, const float* __restrict__ pmax,
    const float* __restrict__ w, const float* __restrict__ b,
    float* __restrict__ z1)
{
    __shared__ float ps[16][H2];
    const int tid = threadIdx.x;
    const int row0 = blockIdx.x * 16;
    for (int i = tid; i < 16 * H2; i += 128) {
        int r = i >> 8, k = i & 255;
        ps[r][k] = (k < HD) ? pmean[(row0 + r) * HD + k]
                            : pmax[(row0 + r) * HD + k - HD];
    }
    __syncthreads();
    const int cp = tid & 63, rg = tid >> 6;
    float a0[8], a1[8];
    #pragma unroll
    for (int r = 0; r < 8; ++r) { a0[r] = 0.f; a1[r] = 0.f; }
    for (int kk = 0; kk < 64; ++kk) {
        float w00 = w[(kk * 4 + 0) * HD + cp];
        float w01 = w[(kk * 4 + 1) * HD + cp];
        float w02 = w[(kk * 4 + 2) * HD + cp];
        float w03 = w[(kk * 4 + 3) * HD + cp];
        float w10 = w[(kk * 4 + 0) * HD + cp + 64];
        float w11 = w[(kk * 4 + 1) * HD + cp + 64];
        float w12 = w[(kk * 4 + 2) * HD + cp + 64];
        float w13 = w[(kk * 4 + 3) * HD + cp + 64];
        #pragma unroll
        for (int r = 0; r < 8; ++r) {
            float4 z4 = *(const float4*)(&ps[rg * 8 + r][kk * 4]);
            a0[r] += z4.x * w00; a0[r] += z4.y * w01;
            a0[r] += z4.z * w02; a0[r] += z4.w * w03;
            a1[r] += z4.x * w10; a1[r] += z4.y * w11;
            a1[r] += z4.z * w12; a1[r] += z4.w * w13;
        }
    }
    const float bb0 = b[cp], bb1 = b[cp + 64];
    #pragma unroll
    for (int r = 0; r < 8; ++r) {
        int row = row0 + rg * 8 + r;
        z1[row * HD + cp]      = fmaxf(a0[r] + bb0, 0.f);
        z1[row * HD + cp + 64] = fmaxf(a1[r] + bb1, 0.f);
    }
}

// --------- column stats for classifier BN (small, atomics fine) --------------
__global__ __launch_bounds__(256) void k_colstats(
    const float* __restrict__ a, int nrows,
    float* __restrict__ ssum, float* __restrict__ ssumsq)
{
    const int tid = threadIdx.x;
    const int col = tid & 127;
    const int rsub = tid >> 7;
    const int r0 = blockIdx.x * 500;
    float s = 0.f, ss = 0.f;
    for (int i = rsub; i < 500; i += 2) {
        int r = r0 + i;
        if (r < nrows) {
            float v = a[r * HD + col];
            s += v; ss += v * v;
        }
    }
    atomicAdd(&ssum[col], s);
    atomicAdd(&ssumsq[col], ss);
}

__global__ void k_bnprep(float* __restrict__ ssum, float* __restrict__ ssumsq,
                         const float* __restrict__ g, const float* __restrict__ b,
                         float* __restrict__ scale, float* __restrict__ shift,
                         float invn)
{
    int c = threadIdx.x;
    if (c < HD) {
        float mean = ssum[c] * invn;
        float var = ssumsq[c] * invn - mean * mean;
        float sc = g[c] * rsqrtf(var + 1e-5f);
        scale[c] = sc;
        shift[c] = b[c] - mean * sc;
    }
}

// ---------------- classifier GEMM2: out = bn(z1) @ W2 + b2 --------------------
__global__ __launch_bounds__(256) void k_cls2(
    const float* __restrict__ z1, const float* __restrict__ scale,
    const float* __restrict__ shift, const float* __restrict__ w,
    const float* __restrict__ b, float* __restrict__ outp)
{
    __shared__ float zs[16][HD];
    const int tid = threadIdx.x;
    const int row0 = blockIdx.x * 16;
    for (int i = tid; i < 16 * HD; i += 256) {
        int r = i >> 7, k = i & 127;
        zs[r][k] = z1[(row0 + r) * HD + k] * scale[k] + shift[k];
    }
    __syncthreads();
    #pragma unroll
    for (int cpass = 0; cpass < 2; ++cpass) {
        int c = tid + cpass * 256;
        if (c < NC) {
            float acc[16];
            float bb = b[c];
            #pragma unroll
            for (int r = 0; r < 16; ++r) acc[r] = bb;
            for (int k = 0; k < HD; ++k) {
                float wv = w[k * NC + c];
                #pragma unroll
                for (int r = 0; r < 16; ++r) acc[r] += zs[r][k] * wv;
            }
            #pragma unroll
            for (int r = 0; r < 16; ++r) outp[(size_t)(row0 + r) * NC + c] = acc[r];
        }
    }
}

extern "C" void kernel_launch(void* const* d_in, const int* in_sizes, int n_in,
                              void* d_out, int out_size, void* d_ws, size_t ws_size,
                              hipStream_t stream)
{
    const float* x       = (const float*)d_in[0];
    const int*   ei      = (const int*)  d_in[1];
    const float* eattr   = (const float*)d_in[2];
    const int*   batch   = (const int*)  d_in[3];
    const float* node_w  = (const float*)d_in[4];
    const float* node_b  = (const float*)d_in[5];
    const float* edge_w  = (const float*)d_in[6];
    const float* edge_b  = (const float*)d_in[7];
    const float* conv_w1 = (const float*)d_in[8];
    const float* conv_b1 = (const float*)d_in[9];
    const float* bn1g    = (const float*)d_in[10];
    const float* bn1b    = (const float*)d_in[11];
    const float* conv_w2 = (const float*)d_in[12];
    const float* conv_b2 = (const float*)d_in[13];
    const float* bng     = (const float*)d_in[14];
    const float* bnb     = (const float*)d_in[15];
    const float* cw1     = (const float*)d_in[16];
    const float* cb1     = (const float*)d_in[17];
    const float* cbg     = (const float*)d_in[18];
    const float* cbb     = (const float*)d_in[19];
    const float* cw2     = (const float*)d_in[20];
    const float* cb2     = (const float*)d_in[21];
    float* out = (float*)d_out;
    float* ws  = (float*)d_ws;

    // ---- workspace layout (floats), total ~52.3M floats = 209 MB ----
    float* h   = ws;                          // 25,600,000
    float* agg = h + (size_t)NN * HD;         // 25,600,000 (aliased as u)
    float* z1  = agg + (size_t)NN * HD;       // 1,048,576
    float* st  = z1 + (size_t)NG * HD;        // stats region
    float* u   = agg;

    float* M       = st;            // 16384
    float* colz    = st + 16384;    // 128
    float* uslotS  = st + 16512;    // 8192
    float* uslotSS = st + 24704;    // 8192
    float* clsS    = st + 32896;    // 128
    float* clsSS   = st + 33024;    // 128
    float* scale1  = st + 33152;    // 256
    float* shift1  = st + 33408;    // 256
    float* scale2  = st + 33664;    // 128
    float* shift2  = st + 33792;    // 128
    float* scalec  = st + 33920;    // 128
    float* shiftc  = st + 34048;    // 128

    // pool outputs live in d_out scratch (consumed before k_cls2 overwrites)
    float* pmean = out;
    float* pmax  = out + (size_t)NG * HD;

    // zero M + colz + uslots + cls sums (re-poisoned to 0xAA before every call)
    k_zero<<<(33152 + 255) / 256, 256, 0, stream>>>(st, 33152);

    k_node_encode<<<NN / 32, 256, 0, stream>>>(x, node_w, node_b, h, agg);

    for (int l = 0; l < 4; ++l) {
        if (l > 0)   // re-zero M + colz for this layer
            k_zero<<<(16512 + 255) / 256, 256, 0, stream>>>(st, 16512);
        k_msg_agg<<<NE / 32, 256, 0, stream>>>(h, ei, eattr, edge_w, edge_b, agg);
        k_zstats<<<(NN + 127) / 128, 256, 0, stream>>>(h, agg, M, colz);
        k_bnprep1<<<H2, 128, 0, stream>>>(M, colz,
                                          conv_w1 + (size_t)l * HD * H2,
                                          conv_b1 + (size_t)l * H2,
                                          bn1g + (size_t)l * H2, bn1b + (size_t)l * H2,
                                          scale1, shift1);
        k_fused<<<NN / 16, 128, 0, stream>>>(h, agg,
                                             conv_w1 + (size_t)l * HD * H2,
                                             conv_b1 + (size_t)l * H2,
                                             scale1, shift1,
                                             conv_w2 + (size_t)l * H2 * HD,
                                             conv_b2 + (size_t)l * HD,
                                             u, uslotS, uslotSS);
        k_bnprep2<<<1, 128, 0, stream>>>(uslotS, uslotSS,
                                         bng + (size_t)l * HD, bnb + (size_t)l * HD,
                                         scale2, shift2);
        k_norm<<<(NN * HD / 4) / 256, 256, 0, stream>>>(scale2, shift2, h, u);
    }

    k_pool<<<NG, 128, 0, stream>>>(h, batch, pmean, pmax);
    k_cls1<<<NG / 16, 128, 0, stream>>>(pmean, pmax, cw1, cb1, z1);
    k_colstats<<<17, 256, 0, stream>>>(z1, NG, clsS, clsSS);
    k_bnprep<<<1, 256, 0, stream>>>(clsS, clsSS, cbg, cbb, scalec, shiftc, 1.f / NG);
    k_cls2<<<NG / 16, 256, 0, stream>>>(z1, scalec, shiftc, cw2, cb2, out);
}

// Round 4
// 3658.225 us; speedup vs baseline: 1.7705x; 1.7705x over previous
//
#include <hip/hip_runtime.h>

#define NN 200000
#define NE 400000
#define NG 8192
#define HD 128
#define H2 256
#define ND 80
#define NC 500
#define ZBLK 240          // zstats blocks (Mpart fits in d_out: 240*16384+240*128 < 4096000)
#define NCHUNK 6250       // NN / 32 exactly

// ------------------------------ zero helper ----------------------------------
__global__ void k_zero(float* p, int n) {
    int i = blockIdx.x * 256 + threadIdx.x;
    if (i < n) p[i] = 0.f;
}

// ---------------- node encoder: h = x @ node_w + node_b ; agg = 0 -------------
__global__ __launch_bounds__(256) void k_node_encode(
    const float* __restrict__ x, const float* __restrict__ w,
    const float* __restrict__ b, float* __restrict__ h, float* __restrict__ agg)
{
    __shared__ float ws[ND][HD];   // 40 KB
    __shared__ float xs[32][ND];   // 10 KB
    const int tid = threadIdx.x;
    for (int i = tid; i < ND * HD; i += 256) ws[i >> 7][i & 127] = w[i];
    const int row0 = blockIdx.x * 32;
    for (int i = tid; i < 32 * ND; i += 256) {
        int r = i / ND, c = i % ND;
        xs[r][c] = x[(size_t)(row0 + r) * ND + c];
    }
    __syncthreads();
    const int col = tid & 127, rs = tid >> 7;
    const float bias = b[col];
    for (int it = 0; it < 16; ++it) {
        int rl = it * 2 + rs;
        float acc = bias;
        #pragma unroll
        for (int k = 0; k < ND; ++k) acc += xs[rl][k] * ws[k][col];
        size_t gi = (size_t)(row0 + rl) * HD + col;
        h[gi] = acc;
        agg[gi] = 0.f;
    }
}

// ------- message + aggregate: agg[dst] += relu(h[src] + e_attr@ew + eb) ------
__global__ __launch_bounds__(256) void k_msg_agg(
    const float* __restrict__ h, const int* __restrict__ ei,
    const float* __restrict__ eattr, const float* __restrict__ ew,
    const float* __restrict__ eb, float* __restrict__ agg)
{
    __shared__ float ews[6][HD];
    __shared__ float ebs[HD];
    const int tid = threadIdx.x;
    for (int i = tid; i < 6 * HD; i += 256) ews[i >> 7][i & 127] = ew[i];
    if (tid < HD) ebs[tid] = eb[tid];
    __syncthreads();
    const int col = tid & 127, es = tid >> 7;
    const int e0 = blockIdx.x * 32;
    for (int it = 0; it < 16; ++it) {
        int e = e0 + it * 2 + es;
        int src = ei[e], dst = ei[NE + e];
        float a0 = eattr[e * 6 + 0], a1 = eattr[e * 6 + 1], a2 = eattr[e * 6 + 2];
        float a3 = eattr[e * 6 + 3], a4 = eattr[e * 6 + 4], a5 = eattr[e * 6 + 5];
        float m = h[(size_t)src * HD + col] + ebs[col]
                + a0 * ews[0][col] + a1 * ews[1][col] + a2 * ews[2][col]
                + a3 * ews[3][col] + a4 * ews[4][col] + a5 * ews[5][col];
        m = fmaxf(m, 0.f);
        atomicAdd(&agg[(size_t)dst * HD + col], m);
    }
}

// ---- Z-stats v2: per-block partials of M = Z'Z (128x128) and colsum(Z) ------
// Z = h + agg. 240 persistent blocks, 32-row LDS chunks, register prefetch.
// Thread tile 16x4: i0=(tid>>5)*16 (broadcast reads), j0=(tid&31)*4 (conflict-free).
__global__ __launch_bounds__(256) void k_zstats2(
    const float* __restrict__ h, const float* __restrict__ agg,
    float* __restrict__ Mpart, float* __restrict__ colzPart)
{
    __shared__ float zs[32][HD];      // 16 KB
    __shared__ float cred[8][HD];     // 4 KB colsum reduction
    const int tid = threadIdx.x;
    const int bid = blockIdx.x;
    const int i0 = (tid >> 5) * 16;
    const int j0 = (tid & 31) * 4;
    const int lrow = tid >> 5;        // 0..7 : this thread's load row group
    const int lc4  = tid & 31;        // this thread's load column (float4)

    float acc[16][4];
    #pragma unroll
    for (int a = 0; a < 16; ++a)
        #pragma unroll
        for (int b = 0; b < 4; ++b) acc[a][b] = 0.f;
    float4 csum = make_float4(0.f, 0.f, 0.f, 0.f);

    // prologue: load first chunk into registers
    float4 pv[4];
    int chunk = bid;
    {
        const size_t r0 = (size_t)chunk * 32;
        #pragma unroll
        for (int i = 0; i < 4; ++i) {
            size_t gi = (r0 + lrow + i * 8) * HD + lc4 * 4;
            float4 hv = *(const float4*)(h + gi);
            float4 av = *(const float4*)(agg + gi);
            pv[i] = make_float4(hv.x + av.x, hv.y + av.y, hv.z + av.z, hv.w + av.w);
        }
    }

    while (chunk < NCHUNK) {
        __syncthreads();   // zs free to overwrite
        #pragma unroll
        for (int i = 0; i < 4; ++i) {
            *(float4*)(&zs[lrow + i * 8][lc4 * 4]) = pv[i];
            csum.x += pv[i].x; csum.y += pv[i].y;
            csum.z += pv[i].z; csum.w += pv[i].w;
        }
        __syncthreads();
        int nxt = chunk + ZBLK;
        if (nxt < NCHUNK) {     // prefetch next chunk (overlaps compute)
            const size_t r0 = (size_t)nxt * 32;
            #pragma unroll
            for (int i = 0; i < 4; ++i) {
                size_t gi = (r0 + lrow + i * 8) * HD + lc4 * 4;
                float4 hv = *(const float4*)(h + gi);
                float4 av = *(const float4*)(agg + gi);
                pv[i] = make_float4(hv.x + av.x, hv.y + av.y, hv.z + av.z, hv.w + av.w);
            }
        }
        #pragma unroll 8
        for (int r = 0; r < 32; ++r) {
            float4 zj  = *(const float4*)(&zs[r][j0]);
            float4 zi0 = *(const float4*)(&zs[r][i0]);
            float4 zi1 = *(const float4*)(&zs[r][i0 + 4]);
            float4 zi2 = *(const float4*)(&zs[r][i0 + 8]);
            float4 zi3 = *(const float4*)(&zs[r][i0 + 12]);
            float zi[16] = {zi0.x, zi0.y, zi0.z, zi0.w,
                            zi1.x, zi1.y, zi1.z, zi1.w,
                            zi2.x, zi2.y, zi2.z, zi2.w,
                            zi3.x, zi3.y, zi3.z, zi3.w};
            #pragma unroll
            for (int a = 0; a < 16; ++a) {
                acc[a][0] += zi[a] * zj.x;
                acc[a][1] += zi[a] * zj.y;
                acc[a][2] += zi[a] * zj.z;
                acc[a][3] += zi[a] * zj.w;
            }
        }
        chunk = nxt;
    }

    // write M partial (no atomics)
    float* mp = Mpart + (size_t)bid * 16384;
    #pragma unroll
    for (int a = 0; a < 16; ++a)
        *(float4*)(mp + (i0 + a) * HD + j0) =
            make_float4(acc[a][0], acc[a][1], acc[a][2], acc[a][3]);

    // colsum partial: reduce 8 row-groups per column
    *(float4*)(&cred[lrow][lc4 * 4]) = csum;
    __syncthreads();
    if (tid < HD) {
        float s = 0.f;
        #pragma unroll
        for (int k = 0; k < 8; ++k) s += cred[k][tid];
        colzPart[bid * HD + tid] = s;
    }
}

// ---- reduce partials: M[idx] = sum_b Mpart[b][idx]; colz likewise -----------
__global__ __launch_bounds__(256) void k_mreduce(
    const float* __restrict__ Mpart, const float* __restrict__ colzPart,
    float* __restrict__ M, float* __restrict__ colz)
{
    int idx = blockIdx.x * 256 + threadIdx.x;
    if (idx < 16384) {
        float s = 0.f;
        for (int b = 0; b < ZBLK; ++b) s += Mpart[(size_t)b * 16384 + idx];
        M[idx] = s;
    } else if (idx < 16384 + HD) {
        int c = idx - 16384;
        float s = 0.f;
        for (int b = 0; b < ZBLK; ++b) s += colzPart[b * HD + c];
        colz[c] = s;
    }
}

// -- BN1 prep from sufficient stats: var(Z@wc) = wc'M wc/N - (colz.wc/N)^2 ----
__global__ __launch_bounds__(128) void k_bnprep1(
    const float* __restrict__ M, const float* __restrict__ colz,
    const float* __restrict__ w1p, const float* __restrict__ b1p,
    const float* __restrict__ g, const float* __restrict__ b,
    float* __restrict__ scale, float* __restrict__ shift)
{
    __shared__ float wcs[128];
    __shared__ float red[128];
    __shared__ float red2[128];
    const int c = blockIdx.x;      // 0..255 output column
    const int j = threadIdx.x;     // 0..127
    float wc = w1p[j * H2 + c];
    wcs[j] = wc;
    __syncthreads();
    float inner = 0.f;
    for (int k = 0; k < 128; ++k) inner += M[j * HD + k] * wcs[k];
    red[j] = wc * inner;
    red2[j] = colz[j] * wc;
    __syncthreads();
    for (int s = 64; s > 0; s >>= 1) {
        if (j < s) { red[j] += red[j + s]; red2[j] += red2[j + s]; }
        __syncthreads();
    }
    if (j == 0) {
        const float invn = 1.f / NN;
        float q = red[0] * invn;
        float d = red2[0] * invn;
        float var = q - d * d;
        float mean = d + b1p[c];
        float sc = g[c] * rsqrtf(var + 1e-5f);
        scale[c] = sc;
        shift[c] = b[c] - mean * sc;
    }
}

// ---- fused conv: u = relu(bn1(Z@W1+b1)) @ W2 + b2 ; accumulate u col stats --
// u may alias agg (each block reads then writes only its own 16 rows).
__global__ __launch_bounds__(128) void k_fused(
    const float* __restrict__ h, const float* agg,
    const float* __restrict__ w1p, const float* __restrict__ b1p,
    const float* __restrict__ scale1, const float* __restrict__ shift1,
    const float* __restrict__ w2p, const float* __restrict__ b2p,
    float* u, float* __restrict__ uslotS, float* __restrict__ uslotSS)
{
    __shared__ float zs[16][HD];    // 8 KB
    __shared__ float ys[16][H2];    // 16 KB
    __shared__ float sred[2][HD];   // 1 KB
    __shared__ float ssred[2][HD];  // 1 KB
    const int tid = threadIdx.x;
    const int row0 = blockIdx.x * 16;
    for (int i = tid; i < 16 * HD; i += 128) {
        size_t gi = (size_t)row0 * HD + i;
        zs[i >> 7][i & 127] = h[gi] + agg[gi];
    }
    __syncthreads();
    // phase A: t = zs @ W1 (cols c0=tid, c1=tid+128), 16-row accumulators
    const int c0 = tid, c1 = tid + 128;
    float a0[16], a1[16];
    #pragma unroll
    for (int r = 0; r < 16; ++r) { a0[r] = 0.f; a1[r] = 0.f; }
    for (int kk = 0; kk < 32; ++kk) {
        float w00 = w1p[(kk * 4 + 0) * H2 + c0];
        float w01 = w1p[(kk * 4 + 1) * H2 + c0];
        float w02 = w1p[(kk * 4 + 2) * H2 + c0];
        float w03 = w1p[(kk * 4 + 3) * H2 + c0];
        float w10 = w1p[(kk * 4 + 0) * H2 + c1];
        float w11 = w1p[(kk * 4 + 1) * H2 + c1];
        float w12 = w1p[(kk * 4 + 2) * H2 + c1];
        float w13 = w1p[(kk * 4 + 3) * H2 + c1];
        #pragma unroll
        for (int r = 0; r < 16; ++r) {
            float4 z4 = *(const float4*)(&zs[r][kk * 4]);
            a0[r] += z4.x * w00; a0[r] += z4.y * w01;
            a0[r] += z4.z * w02; a0[r] += z4.w * w03;
            a1[r] += z4.x * w10; a1[r] += z4.y * w11;
            a1[r] += z4.z * w12; a1[r] += z4.w * w13;
        }
    }
    const float sc0 = scale1[c0], sh0 = shift1[c0];
    const float sc1 = scale1[c1], sh1 = shift1[c1];
    const float tb0 = b1p[c0], tb1 = b1p[c1];
    #pragma unroll
    for (int r = 0; r < 16; ++r) {
        ys[r][c0] = fmaxf((a0[r] + tb0) * sc0 + sh0, 0.f);
        ys[r][c1] = fmaxf((a1[r] + tb1) * sc1 + sh1, 0.f);
    }
    __syncthreads();
    // phase B: u = ys @ W2 (cols cp, cp+64; rows rg*8..rg*8+7)
    const int cp = tid & 63, rg = tid >> 6;
    float u0[8], u1[8];
    #pragma unroll
    for (int r = 0; r < 8; ++r) { u0[r] = 0.f; u1[r] = 0.f; }
    for (int kk = 0; kk < 64; ++kk) {
        float w00 = w2p[(kk * 4 + 0) * HD + cp];
        float w01 = w2p[(kk * 4 + 1) * HD + cp];
        float w02 = w2p[(kk * 4 + 2) * HD + cp];
        float w03 = w2p[(kk * 4 + 3) * HD + cp];
        float w10 = w2p[(kk * 4 + 0) * HD + cp + 64];
        float w11 = w2p[(kk * 4 + 1) * HD + cp + 64];
        float w12 = w2p[(kk * 4 + 2) * HD + cp + 64];
        float w13 = w2p[(kk * 4 + 3) * HD + cp + 64];
        #pragma unroll
        for (int r = 0; r < 8; ++r) {
            float4 z4 = *(const float4*)(&ys[rg * 8 + r][kk * 4]);
            u0[r] += z4.x * w00; u0[r] += z4.y * w01;
            u0[r] += z4.z * w02; u0[r] += z4.w * w03;
            u1[r] += z4.x * w10; u1[r] += z4.y * w11;
            u1[r] += z4.z * w12; u1[r] += z4.w * w13;
        }
    }
    const float ub0 = b2p[cp], ub1 = b2p[cp + 64];
    float s0 = 0.f, ss0 = 0.f, s1 = 0.f, ss1 = 0.f;
    #pragma unroll
    for (int r = 0; r < 8; ++r) {
        int row = row0 + rg * 8 + r;
        float v0 = u0[r] + ub0;
        float v1 = u1[r] + ub1;
        u[(size_t)row * HD + cp]      = v0;
        u[(size_t)row * HD + cp + 64] = v1;
        s0 += v0; ss0 += v0 * v0;
        s1 += v1; ss1 += v1 * v1;
    }
    sred[rg][cp] = s0;       ssred[rg][cp] = ss0;
    sred[rg][cp + 64] = s1;  ssred[rg][cp + 64] = ss1;
    __syncthreads();
    if (tid < HD) {
        int slot = blockIdx.x & 63;
        atomicAdd(&uslotS[slot * HD + tid],  sred[0][tid] + sred[1][tid]);
        atomicAdd(&uslotSS[slot * HD + tid], ssred[0][tid] + ssred[1][tid]);
    }
}

// ------------- BN2 prep: reduce 64 slots, emit scale/shift, zero slots -------
__global__ __launch_bounds__(128) void k_bnprep2(
    float* __restrict__ uslotS, float* __restrict__ uslotSS,
    const float* __restrict__ g, const float* __restrict__ b,
    float* __restrict__ scale, float* __restrict__ shift)
{
    const int c = threadIdx.x;   // 0..127
    float s = 0.f, ss = 0.f;
    for (int k = 0; k < 64; ++k) {
        s  += uslotS[k * HD + c];
        ss += uslotSS[k * HD + c];
        uslotS[k * HD + c] = 0.f;
        uslotSS[k * HD + c] = 0.f;
    }
    const float invn = 1.f / NN;
    float mean = s * invn;
    float var = ss * invn - mean * mean;
    float sc = g[c] * rsqrtf(var + 1e-5f);
    scale[c] = sc;
    shift[c] = b[c] - mean * sc;
}

// --------- normalize+relu: h = relu(u*scale+shift); zero u (=agg) ------------
__global__ __launch_bounds__(256) void k_norm(
    const float* __restrict__ scale, const float* __restrict__ shift,
    float* __restrict__ h, float* uio)
{
    int idx = blockIdx.x * 256 + threadIdx.x;   // float4 index
    float4 v = ((const float4*)uio)[idx];
    int c = (idx * 4) & 127;
    v.x = fmaxf(v.x * scale[c + 0] + shift[c + 0], 0.f);
    v.y = fmaxf(v.y * scale[c + 1] + shift[c + 1], 0.f);
    v.z = fmaxf(v.z * scale[c + 2] + shift[c + 2], 0.f);
    v.w = fmaxf(v.w * scale[c + 3] + shift[c + 3], 0.f);
    ((float4*)h)[idx] = v;
    ((float4*)uio)[idx] = make_float4(0.f, 0.f, 0.f, 0.f);
}

// -------- pool: per-graph mean & max over sorted batch (binary search) --------
__global__ __launch_bounds__(128) void k_pool(
    const float* __restrict__ h, const int* __restrict__ batch,
    float* __restrict__ pmean, float* __restrict__ pmax)
{
    const int g = blockIdx.x;
    const int tid = threadIdx.x;
    int lo = 0, hi = NN;
    while (lo < hi) { int mid = (lo + hi) >> 1; if (batch[mid] < g) lo = mid + 1; else hi = mid; }
    const int start = lo;
    hi = NN;
    while (lo < hi) { int mid = (lo + hi) >> 1; if (batch[mid] < g + 1) lo = mid + 1; else hi = mid; }
    const int end = lo;
    float s = 0.f, m = 0.f;
    for (int i = start; i < end; ++i) {
        float v = h[(size_t)i * HD + tid];
        s += v; m = fmaxf(m, v);
    }
    float cnt = (float)(end - start);
    pmean[g * HD + tid] = s / fmaxf(cnt, 1.f);
    pmax[g * HD + tid] = m;   // h >= 0 so 0-init matches reference's isfinite fixup
}

// ------------- classifier GEMM1: z1 = relu([mean||max] @ W + b) ---------------
__global__ __launch_bounds__(128) void k_cls1(
    const float* __restrict__ pmean, const float* __restrict__ pmax,
    const float* __restrict__ w, const float* __restrict__ b,
    float* __restrict__ z1)
{
    __shared__ float ps[16][H2];
    const int tid = threadIdx.x;
    const int row0 = blockIdx.x * 16;
    for (int i = tid; i < 16 * H2; i += 128) {
        int r = i >> 8, k = i & 255;
        ps[r][k] = (k < HD) ? pmean[(row0 + r) * HD + k]
                            : pmax[(row0 + r) * HD + k - HD];
    }
    __syncthreads();
    const int cp = tid & 63, rg = tid >> 6;
    float a0[8], a1[8];
    #pragma unroll
    for (int r = 0; r < 8; ++r) { a0[r] = 0.f; a1[r] = 0.f; }
    for (int kk = 0; kk < 64; ++kk) {
        float w00 = w[(kk * 4 + 0) * HD + cp];
        float w01 = w[(kk * 4 + 1) * HD + cp];
        float w02 = w[(kk * 4 + 2) * HD + cp];
        float w03 = w[(kk * 4 + 3) * HD + cp];
        float w10 = w[(kk * 4 + 0) * HD + cp + 64];
        float w11 = w[(kk * 4 + 1) * HD + cp + 64];
        float w12 = w[(kk * 4 + 2) * HD + cp + 64];
        float w13 = w[(kk * 4 + 3) * HD + cp + 64];
        #pragma unroll
        for (int r = 0; r < 8; ++r) {
            float4 z4 = *(const float4*)(&ps[rg * 8 + r][kk * 4]);
            a0[r] += z4.x * w00; a0[r] += z4.y * w01;
            a0[r] += z4.z * w02; a0[r] += z4.w * w03;
            a1[r] += z4.x * w10; a1[r] += z4.y * w11;
            a1[r] += z4.z * w12; a1[r] += z4.w * w13;
        }
    }
    const float bb0 = b[cp], bb1 = b[cp + 64];
    #pragma unroll
    for (int r = 0; r < 8; ++r) {
        int row = row0 + rg * 8 + r;
        z1[row * HD + cp]      = fmaxf(a0[r] + bb0, 0.f);
        z1[row * HD + cp + 64] = fmaxf(a1[r] + bb1, 0.f);
    }
}

// --------- column stats for classifier BN (small, atomics fine) --------------
__global__ __launch_bounds__(256) void k_colstats(
    const float* __restrict__ a, int nrows,
    float* __restrict__ ssum, float* __restrict__ ssumsq)
{
    const int tid = threadIdx.x;
    const int col = tid & 127;
    const int rsub = tid >> 7;
    const int r0 = blockIdx.x * 500;
    float s = 0.f, ss = 0.f;
    for (int i = rsub; i < 500; i += 2) {
        int r = r0 + i;
        if (r < nrows) {
            float v = a[r * HD + col];
            s += v; ss += v * v;
        }
    }
    atomicAdd(&ssum[col], s);
    atomicAdd(&ssumsq[col], ss);
}

__global__ void k_bnprep(float* __restrict__ ssum, float* __restrict__ ssumsq,
                         const float* __restrict__ g, const float* __restrict__ b,
                         float* __restrict__ scale, float* __restrict__ shift,
                         float invn)
{
    int c = threadIdx.x;
    if (c < HD) {
        float mean = ssum[c] * invn;
        float var = ssumsq[c] * invn - mean * mean;
        float sc = g[c] * rsqrtf(var + 1e-5f);
        scale[c] = sc;
        shift[c] = b[c] - mean * sc;
    }
}

// ---------------- classifier GEMM2: out = bn(z1) @ W2 + b2 --------------------
__global__ __launch_bounds__(256) void k_cls2(
    const float* __restrict__ z1, const float* __restrict__ scale,
    const float* __restrict__ shift, const float* __restrict__ w,
    const float* __restrict__ b, float* __restrict__ outp)
{
    __shared__ float zs[16][HD];
    const int tid = threadIdx.x;
    const int row0 = blockIdx.x * 16;
    for (int i = tid; i < 16 * HD; i += 256) {
        int r = i >> 7, k = i & 127;
        zs[r][k] = z1[(row0 + r) * HD + k] * scale[k] + shift[k];
    }
    __syncthreads();
    #pragma unroll
    for (int cpass = 0; cpass < 2; ++cpass) {
        int c = tid + cpass * 256;
        if (c < NC) {
            float acc[16];
            float bb = b[c];
            #pragma unroll
            for (int r = 0; r < 16; ++r) acc[r] = bb;
            for (int k = 0; k < HD; ++k) {
                float wv = w[k * NC + c];
                #pragma unroll
                for (int r = 0; r < 16; ++r) acc[r] += zs[r][k] * wv;
            }
            #pragma unroll
            for (int r = 0; r < 16; ++r) outp[(size_t)(row0 + r) * NC + c] = acc[r];
        }
    }
}

extern "C" void kernel_launch(void* const* d_in, const int* in_sizes, int n_in,
                              void* d_out, int out_size, void* d_ws, size_t ws_size,
                              hipStream_t stream)
{
    const float* x       = (const float*)d_in[0];
    const int*   ei      = (const int*)  d_in[1];
    const float* eattr   = (const float*)d_in[2];
    const int*   batch   = (const int*)  d_in[3];
    const float* node_w  = (const float*)d_in[4];
    const float* node_b  = (const float*)d_in[5];
    const float* edge_w  = (const float*)d_in[6];
    const float* edge_b  = (const float*)d_in[7];
    const float* conv_w1 = (const float*)d_in[8];
    const float* conv_b1 = (const float*)d_in[9];
    const float* bn1g    = (const float*)d_in[10];
    const float* bn1b    = (const float*)d_in[11];
    const float* conv_w2 = (const float*)d_in[12];
    const float* conv_b2 = (const float*)d_in[13];
    const float* bng     = (const float*)d_in[14];
    const float* bnb     = (const float*)d_in[15];
    const float* cw1     = (const float*)d_in[16];
    const float* cb1     = (const float*)d_in[17];
    const float* cbg     = (const float*)d_in[18];
    const float* cbb     = (const float*)d_in[19];
    const float* cw2     = (const float*)d_in[20];
    const float* cb2     = (const float*)d_in[21];
    float* out = (float*)d_out;
    float* ws  = (float*)d_ws;

    // ---- workspace layout (floats), total ~52.3M floats = 209 MB ----
    float* h   = ws;                          // 25,600,000
    float* agg = h + (size_t)NN * HD;         // 25,600,000 (aliased as u)
    float* z1  = agg + (size_t)NN * HD;       // 1,048,576
    float* st  = z1 + (size_t)NG * HD;        // stats region
    float* u   = agg;

    float* uslotS  = st;            // 8192
    float* uslotSS = st + 8192;     // 8192
    float* clsS    = st + 16384;    // 128
    float* clsSS   = st + 16512;    // 128
    float* scale1  = st + 16640;    // 256
    float* shift1  = st + 16896;    // 256
    float* scale2  = st + 17152;    // 128
    float* shift2  = st + 17280;    // 128
    float* scalec  = st + 17408;    // 128
    float* shiftc  = st + 17536;    // 128
    float* M       = st + 17664;    // 16384
    float* colz    = st + 34048;    // 128

    // Mpart/colzPart live in d_out scratch during the layer loop (3,962,880
    // floats <= out_size 4,096,000); pool reuses d_out afterwards (disjoint
    // in time), and k_cls2 fully overwrites d_out at the end.
    float* Mpart    = out;                       // 240 * 16384
    float* colzPart = out + (size_t)ZBLK * 16384; // 240 * 128
    float* pmean = out;
    float* pmax  = out + (size_t)NG * HD;

    // zero uslots + cls sums once (re-poisoned to 0xAA before every call)
    k_zero<<<(16640 + 255) / 256, 256, 0, stream>>>(st, 16640);

    k_node_encode<<<NN / 32, 256, 0, stream>>>(x, node_w, node_b, h, agg);

    for (int l = 0; l < 4; ++l) {
        k_msg_agg<<<NE / 32, 256, 0, stream>>>(h, ei, eattr, edge_w, edge_b, agg);
        k_zstats2<<<ZBLK, 256, 0, stream>>>(h, agg, Mpart, colzPart);
        k_mreduce<<<(16384 + HD + 255) / 256, 256, 0, stream>>>(Mpart, colzPart, M, colz);
        k_bnprep1<<<H2, 128, 0, stream>>>(M, colz,
                                          conv_w1 + (size_t)l * HD * H2,
                                          conv_b1 + (size_t)l * H2,
                                          bn1g + (size_t)l * H2, bn1b + (size_t)l * H2,
                                          scale1, shift1);
        k_fused<<<NN / 16, 128, 0, stream>>>(h, agg,
                                             conv_w1 + (size_t)l * HD * H2,
                                             conv_b1 + (size_t)l * H2,
                                             scale1, shift1,
                                             conv_w2 + (size_t)l * H2 * HD,
                                             conv_b2 + (size_t)l * HD,
                                             u, uslotS, uslotSS);
        k_bnprep2<<<1, 128, 0, stream>>>(uslotS, uslotSS,
                                         bng + (size_t)l * HD, bnb + (size_t)l * HD,
                                         scale2, shift2);
        k_norm<<<(NN * HD / 4) / 256, 256, 0, stream>>>(scale2, shift2, h, u);
    }

    k_pool<<<NG, 128, 0, stream>>>(h, batch, pmean, pmax);
    k_cls1<<<NG / 16, 128, 0, stream>>>(pmean, pmax, cw1, cb1, z1);
    k_colstats<<<17, 256, 0, stream>>>(z1, NG, clsS, clsSS);
    k_bnprep<<<1, 256, 0, stream>>>(clsS, clsSS, cbg, cbb, scalec, shiftc, 1.f / NG);
    k_cls2<<<NG / 16, 256, 0, stream>>>(z1, scalec, shiftc, cw2, cb2, out);
}

// Round 6
// 2699.360 us; speedup vs baseline: 2.3995x; 1.3552x over previous
//
#include <hip/hip_runtime.h>

#define NN 200000
#define NE 400000
#define NG 8192
#define HD 128
#define H2 256
#define ND 80
#define NC 500
#define ZBLK 240          // zstats blocks (Mpart+colzPart fit in d_out)
#define NCHUNK 6250       // NN / 32 exactly

typedef short bf16x8 __attribute__((ext_vector_type(8)));
typedef short bf16x4 __attribute__((ext_vector_type(4)));
typedef float f32x4  __attribute__((ext_vector_type(4)));

static __device__ __forceinline__ short f2bf(float f) {
    unsigned u = __float_as_uint(f);
    unsigned r = (u + 0x7fffu + ((u >> 16) & 1u)) >> 16;
    return (short)r;
}
static __device__ __forceinline__ float bf2f(short s) {
    return __uint_as_float(((unsigned)(unsigned short)s) << 16);
}

// ------------------------------ zero helper ----------------------------------
__global__ void k_zero(float* p, int n) {
    int i = blockIdx.x * 256 + threadIdx.x;
    if (i < n) p[i] = 0.f;
}

// ---------------- node encoder: h = x @ node_w + node_b ; agg = 0 -------------
__global__ __launch_bounds__(256) void k_node_encode(
    const float* __restrict__ x, const float* __restrict__ w,
    const float* __restrict__ b, float* __restrict__ h, float* __restrict__ agg)
{
    __shared__ float ws[ND][HD];   // 40 KB
    __shared__ float xs[32][ND];   // 10 KB
    const int tid = threadIdx.x;
    for (int i = tid; i < ND * HD; i += 256) ws[i >> 7][i & 127] = w[i];
    const int row0 = blockIdx.x * 32;
    for (int i = tid; i < 32 * ND; i += 256) {
        int r = i / ND, c = i % ND;
        xs[r][c] = x[(size_t)(row0 + r) * ND + c];
    }
    __syncthreads();
    const int col = tid & 127, rs = tid >> 7;
    const float bias = b[col];
    for (int it = 0; it < 16; ++it) {
        int rl = it * 2 + rs;
        float acc = bias;
        #pragma unroll
        for (int k = 0; k < ND; ++k) acc += xs[rl][k] * ws[k][col];
        size_t gi = (size_t)(row0 + rl) * HD + col;
        h[gi] = acc;
        agg[gi] = 0.f;
    }
}

// ------- message + aggregate: agg[dst] += relu(h[src] + e_attr@ew + eb) ------
__global__ __launch_bounds__(256) void k_msg_agg(
    const float* __restrict__ h, const int* __restrict__ ei,
    const float* __restrict__ eattr, const float* __restrict__ ew,
    const float* __restrict__ eb, float* __restrict__ agg)
{
    __shared__ float ews[6][HD];
    __shared__ float ebs[HD];
    const int tid = threadIdx.x;
    for (int i = tid; i < 6 * HD; i += 256) ews[i >> 7][i & 127] = ew[i];
    if (tid < HD) ebs[tid] = eb[tid];
    __syncthreads();
    const int col = tid & 127, es = tid >> 7;
    const int e0 = blockIdx.x * 32;
    for (int it = 0; it < 16; ++it) {
        int e = e0 + it * 2 + es;
        int src = ei[e], dst = ei[NE + e];
        float a0 = eattr[e * 6 + 0], a1 = eattr[e * 6 + 1], a2 = eattr[e * 6 + 2];
        float a3 = eattr[e * 6 + 3], a4 = eattr[e * 6 + 4], a5 = eattr[e * 6 + 5];
        float m = h[(size_t)src * HD + col] + ebs[col]
                + a0 * ews[0][col] + a1 * ews[1][col] + a2 * ews[2][col]
                + a3 * ews[3][col] + a4 * ews[4][col] + a5 * ews[5][col];
        m = fmaxf(m, 0.f);
        atomicAdd(&agg[(size_t)dst * HD + col], m);
    }
}

// ---- Z-stats v2: per-block partials of M = Z'Z (128x128) and colsum(Z) ------
__global__ __launch_bounds__(256) void k_zstats2(
    const float* __restrict__ h, const float* __restrict__ agg,
    float* __restrict__ Mpart, float* __restrict__ colzPart)
{
    __shared__ float zs[32][HD];      // 16 KB
    __shared__ float cred[8][HD];     // 4 KB colsum reduction
    const int tid = threadIdx.x;
    const int bid = blockIdx.x;
    const int i0 = (tid >> 5) * 16;
    const int j0 = (tid & 31) * 4;
    const int lrow = tid >> 5;        // 0..7 : load row group
    const int lc4  = tid & 31;        // load column (float4)

    float acc[16][4];
    #pragma unroll
    for (int a = 0; a < 16; ++a)
        #pragma unroll
        for (int b = 0; b < 4; ++b) acc[a][b] = 0.f;
    float4 csum = make_float4(0.f, 0.f, 0.f, 0.f);

    float4 pv[4];
    int chunk = bid;
    {
        const size_t r0 = (size_t)chunk * 32;
        #pragma unroll
        for (int i = 0; i < 4; ++i) {
            size_t gi = (r0 + lrow + i * 8) * HD + lc4 * 4;
            float4 hv = *(const float4*)(h + gi);
            float4 av = *(const float4*)(agg + gi);
            pv[i] = make_float4(hv.x + av.x, hv.y + av.y, hv.z + av.z, hv.w + av.w);
        }
    }

    while (chunk < NCHUNK) {
        __syncthreads();
        #pragma unroll
        for (int i = 0; i < 4; ++i) {
            *(float4*)(&zs[lrow + i * 8][lc4 * 4]) = pv[i];
            csum.x += pv[i].x; csum.y += pv[i].y;
            csum.z += pv[i].z; csum.w += pv[i].w;
        }
        __syncthreads();
        int nxt = chunk + ZBLK;
        if (nxt < NCHUNK) {
            const size_t r0 = (size_t)nxt * 32;
            #pragma unroll
            for (int i = 0; i < 4; ++i) {
                size_t gi = (r0 + lrow + i * 8) * HD + lc4 * 4;
                float4 hv = *(const float4*)(h + gi);
                float4 av = *(const float4*)(agg + gi);
                pv[i] = make_float4(hv.x + av.x, hv.y + av.y, hv.z + av.z, hv.w + av.w);
            }
        }
        #pragma unroll 8
        for (int r = 0; r < 32; ++r) {
            float4 zj  = *(const float4*)(&zs[r][j0]);
            float4 zi0 = *(const float4*)(&zs[r][i0]);
            float4 zi1 = *(const float4*)(&zs[r][i0 + 4]);
            float4 zi2 = *(const float4*)(&zs[r][i0 + 8]);
            float4 zi3 = *(const float4*)(&zs[r][i0 + 12]);
            float zi[16] = {zi0.x, zi0.y, zi0.z, zi0.w,
                            zi1.x, zi1.y, zi1.z, zi1.w,
                            zi2.x, zi2.y, zi2.z, zi2.w,
                            zi3.x, zi3.y, zi3.z, zi3.w};
            #pragma unroll
            for (int a = 0; a < 16; ++a) {
                acc[a][0] += zi[a] * zj.x;
                acc[a][1] += zi[a] * zj.y;
                acc[a][2] += zi[a] * zj.z;
                acc[a][3] += zi[a] * zj.w;
            }
        }
        chunk = nxt;
    }

    float* mp = Mpart + (size_t)bid * 16384;
    #pragma unroll
    for (int a = 0; a < 16; ++a)
        *(float4*)(mp + (i0 + a) * HD + j0) =
            make_float4(acc[a][0], acc[a][1], acc[a][2], acc[a][3]);

    *(float4*)(&cred[lrow][lc4 * 4]) = csum;
    __syncthreads();
    if (tid < HD) {
        float s = 0.f;
        #pragma unroll
        for (int k = 0; k < 8; ++k) s += cred[k][tid];
        colzPart[bid * HD + tid] = s;
    }
}

// ---- reduce partials ---------------------------------------------------------
__global__ __launch_bounds__(256) void k_mreduce(
    const float* __restrict__ Mpart, const float* __restrict__ colzPart,
    float* __restrict__ M, float* __restrict__ colz)
{
    int idx = blockIdx.x * 256 + threadIdx.x;
    if (idx < 16384) {
        float s = 0.f;
        for (int b = 0; b < ZBLK; ++b) s += Mpart[(size_t)b * 16384 + idx];
        M[idx] = s;
    } else if (idx < 16384 + HD) {
        int c = idx - 16384;
        float s = 0.f;
        for (int b = 0; b < ZBLK; ++b) s += colzPart[b * HD + c];
        colz[c] = s;
    }
}

// -- BN1 prep: var(Z@wc) = wc'M wc/N - (colz.wc/N)^2 ; conv bias b1 cancels ---
__global__ __launch_bounds__(128) void k_bnprep1(
    const float* __restrict__ M, const float* __restrict__ colz,
    const float* __restrict__ w1p,
    const float* __restrict__ g, const float* __restrict__ b,
    float* __restrict__ scale, float* __restrict__ shift)
{
    __shared__ float wcs[128];
    __shared__ float red[128];
    __shared__ float red2[128];
    const int c = blockIdx.x;      // 0..255 output column
    const int j = threadIdx.x;     // 0..127
    float wc = w1p[j * H2 + c];
    wcs[j] = wc;
    __syncthreads();
    float inner = 0.f;
    for (int k = 0; k < 128; ++k) inner += M[j * HD + k] * wcs[k];
    red[j] = wc * inner;
    red2[j] = colz[j] * wc;
    __syncthreads();
    for (int s = 64; s > 0; s >>= 1) {
        if (j < s) { red[j] += red[j + s]; red2[j] += red2[j + s]; }
        __syncthreads();
    }
    if (j == 0) {
        const float invn = 1.f / NN;
        float q = red[0] * invn;
        float d = red2[0] * invn;          // mean of t (without conv bias)
        float var = q - d * d;
        float sc = g[c] * rsqrtf(var + 1e-5f);
        scale[c] = sc;
        shift[c] = b[c] - d * sc;          // conv bias b1 cancels algebraically
    }
}

// -- W fragment preconversion: MFMA-operand-ordered bf16 hi/lo, all 4 layers --
// w1 part [ft 16][kk 4][lane 64][8]: elem = W1[kk*32+(l>>4)*8+j][ft*16+(l&15)]
// w2 part [ft  8][kk 8][lane 64][8]: elem = W2[kk*32+(l>>4)*8+j][ft*16+(l&15)]
__global__ __launch_bounds__(256) void k_wprep(
    const float* __restrict__ w1, const float* __restrict__ w2,
    short* __restrict__ wh, short* __restrict__ wlo)
{
    int id = blockIdx.x * 256 + threadIdx.x;    // 0 .. 4*65536
    int layer = id >> 16, r = id & 65535;
    float v;
    if (r < 32768) {
        int ft = r >> 11, kk = (r >> 9) & 3, l = (r >> 3) & 63, j = r & 7;
        int k = kk * 32 + (l >> 4) * 8 + j, c = ft * 16 + (l & 15);
        v = w1[(size_t)layer * HD * H2 + k * H2 + c];
    } else {
        int r2 = r - 32768;
        int ft = r2 >> 12, kk = (r2 >> 9) & 7, l = (r2 >> 3) & 63, j = r2 & 7;
        int k = kk * 32 + (l >> 4) * 8 + j, c = ft * 16 + (l & 15);
        v = w2[(size_t)layer * H2 * HD + k * HD + c];
    }
    short hi = f2bf(v);
    wh[id] = hi;
    wlo[id] = f2bf(v - bf2f(hi));
}

// ---- fused conv via 3-product bf16 MFMA: u = relu(bn1(Z@W1)) @ W2 + b2 ------
// Transposed form: t^T = W1^T Z^T, u^T = W2^T y^T. 2 waves x 16 nodes = 32/block.
// Z loaded per-lane from global (no LDS stage); y hi/lo in swizzled LDS.
// u may alias agg (block reads/writes only its own 32 rows).
__global__ __launch_bounds__(128) void k_fused_mfma3(
    const float* __restrict__ h, const float* agg,
    const short* __restrict__ w1h, const short* __restrict__ w1l,
    const short* __restrict__ w2h, const short* __restrict__ w2l,
    const float* __restrict__ scale1, const float* __restrict__ shift1,
    const float* __restrict__ b2p, float* u)
{
    __shared__ short ysh[32 * 256];   // 16 KB, XOR-swizzled 16B granules
    __shared__ short ysl[32 * 256];   // 16 KB
    __shared__ float sc1s[H2], sh1s[H2];
    const int tid = threadIdx.x;
    const int row0g = blockIdx.x * 32;
    for (int i = tid; i < H2; i += 128) { sc1s[i] = scale1[i]; sh1s[i] = shift1[i]; }

    const int l = tid & 63, w = tid >> 6;
    const int nq = l >> 4;                 // 0..3
    const int node = w * 16 + (l & 15);    // local node 0..31
    const int nx = node & 7;
    const size_t zbase = (size_t)(row0g + node) * HD;

    // B-frags (Z^T) hi/lo straight from global: Z[node][kk*32+nq*8 .. +8]
    bf16x8 zh[4], zl[4];
    #pragma unroll
    for (int kk = 0; kk < 4; ++kk) {
        int c0 = kk * 32 + nq * 8;
        float4 h0 = *(const float4*)(h + zbase + c0);
        float4 h1 = *(const float4*)(h + zbase + c0 + 4);
        float4 a0 = *(const float4*)(agg + zbase + c0);
        float4 a1 = *(const float4*)(agg + zbase + c0 + 4);
        float z[8] = {h0.x + a0.x, h0.y + a0.y, h0.z + a0.z, h0.w + a0.w,
                      h1.x + a1.x, h1.y + a1.y, h1.z + a1.z, h1.w + a1.w};
        #pragma unroll
        for (int j = 0; j < 8; ++j) {
            short hi = f2bf(z[j]);
            zh[kk][j] = hi;
            zl[kk][j] = f2bf(z[j] - bf2f(hi));
        }
    }
    __syncthreads();   // sc1s/sh1s ready

    // phase A: t^T tiles; epilogue BN1+relu -> ys hi/lo (swizzled)
    #pragma unroll
    for (int ft = 0; ft < 16; ++ft) {
        f32x4 acc = {0.f, 0.f, 0.f, 0.f};
        #pragma unroll
        for (int kk = 0; kk < 4; ++kk) {
            int wi = ((ft * 4 + kk) * 64 + l) * 8;
            bf16x8 ah = *(const bf16x8*)(w1h + wi);
            bf16x8 al = *(const bf16x8*)(w1l + wi);
            acc = __builtin_amdgcn_mfma_f32_16x16x32_bf16(ah, zh[kk], acc, 0, 0, 0);
            acc = __builtin_amdgcn_mfma_f32_16x16x32_bf16(ah, zl[kk], acc, 0, 0, 0);
            acc = __builtin_amdgcn_mfma_f32_16x16x32_bf16(al, zh[kk], acc, 0, 0, 0);
        }
        int f0 = ft * 16 + nq * 4;         // 4 contiguous output features
        float4 scv = *(const float4*)(&sc1s[f0]);
        float4 shv = *(const float4*)(&sh1s[f0]);
        float y0 = fmaxf(acc[0] * scv.x + shv.x, 0.f);
        float y1 = fmaxf(acc[1] * scv.y + shv.y, 0.f);
        float y2 = fmaxf(acc[2] * scv.z + shv.z, 0.f);
        float y3 = fmaxf(acc[3] * scv.w + shv.w, 0.f);
        bf16x4 ph, pl;
        ph[0] = f2bf(y0); pl[0] = f2bf(y0 - bf2f(ph[0]));
        ph[1] = f2bf(y1); pl[1] = f2bf(y1 - bf2f(ph[1]));
        ph[2] = f2bf(y2); pl[2] = f2bf(y2 - bf2f(ph[2]));
        ph[3] = f2bf(y3); pl[3] = f2bf(y3 - bf2f(ph[3]));
        int off = node * 256 + (((f0 >> 3) ^ nx) * 8) + (nq & 1) * 4;
        *(bf16x4*)(&ysh[off]) = ph;
        *(bf16x4*)(&ysl[off]) = pl;
    }
    __syncthreads();

    // phase B: u^T = W2^T y^T (3-product)
    bf16x8 ybh[8], ybl[8];
    #pragma unroll
    for (int kk = 0; kk < 8; ++kk) {
        int off = node * 256 + (((kk * 4 + nq) ^ nx) * 8);
        ybh[kk] = *(const bf16x8*)(&ysh[off]);
        ybl[kk] = *(const bf16x8*)(&ysl[off]);
    }
    #pragma unroll
    for (int ft = 0; ft < 8; ++ft) {
        f32x4 acc = {0.f, 0.f, 0.f, 0.f};
        #pragma unroll
        for (int kk = 0; kk < 8; ++kk) {
            int wi = ((ft * 8 + kk) * 64 + l) * 8;
            bf16x8 ah = *(const bf16x8*)(w2h + wi);
            bf16x8 al = *(const bf16x8*)(w2l + wi);
            acc = __builtin_amdgcn_mfma_f32_16x16x32_bf16(ah, ybh[kk], acc, 0, 0, 0);
            acc = __builtin_amdgcn_mfma_f32_16x16x32_bf16(ah, ybl[kk], acc, 0, 0, 0);
            acc = __builtin_amdgcn_mfma_f32_16x16x32_bf16(al, ybh[kk], acc, 0, 0, 0);
        }
        int f0 = ft * 16 + nq * 4;
        float4 bv = *(const float4*)(b2p + f0);
        float4 o = make_float4(acc[0] + bv.x, acc[1] + bv.y,
                               acc[2] + bv.z, acc[3] + bv.w);
        *(float4*)(&u[(size_t)(row0g + node) * HD + f0]) = o;
    }
}

// --------- u column stats (separate pass; 64-slot atomics) -------------------
__global__ __launch_bounds__(256) void k_ustats(
    const float* __restrict__ u,
    float* __restrict__ uslotS, float* __restrict__ uslotSS)
{
    __shared__ float sS[2][HD], sQ[2][HD];
    const int tid = threadIdx.x;
    const int col = tid & 127, half = tid >> 7;
    size_t r0 = (size_t)blockIdx.x * 500 + half * 250;
    float s = 0.f, ss = 0.f;
    for (int i = 0; i < 250; ++i) {
        float v = u[(r0 + i) * HD + col];
        s += v; ss += v * v;
    }
    sS[half][col] = s; sQ[half][col] = ss;
    __syncthreads();
    if (tid < HD) {
        int slot = blockIdx.x & 63;
        atomicAdd(&uslotS[slot * HD + tid],  sS[0][tid] + sS[1][tid]);
        atomicAdd(&uslotSS[slot * HD + tid], sQ[0][tid] + sQ[1][tid]);
    }
}

// ------------- BN2 prep: reduce 64 slots, emit scale/shift, zero slots -------
__global__ __launch_bounds__(128) void k_bnprep2(
    float* __restrict__ uslotS, float* __restrict__ uslotSS,
    const float* __restrict__ g, const float* __restrict__ b,
    float* __restrict__ scale, float* __restrict__ shift)
{
    const int c = threadIdx.x;   // 0..127
    float s = 0.f, ss = 0.f;
    for (int k = 0; k < 64; ++k) {
        s  += uslotS[k * HD + c];
        ss += uslotSS[k * HD + c];
        uslotS[k * HD + c] = 0.f;
        uslotSS[k * HD + c] = 0.f;
    }
    const float invn = 1.f / NN;
    float mean = s * invn;
    float var = ss * invn - mean * mean;
    float sc = g[c] * rsqrtf(var + 1e-5f);
    scale[c] = sc;
    shift[c] = b[c] - mean * sc;
}

// --------- normalize+relu: h = relu(u*scale+shift); zero u (=agg) ------------
__global__ __launch_bounds__(256) void k_norm(
    const float* __restrict__ scale, const float* __restrict__ shift,
    float* __restrict__ h, float* uio)
{
    int idx = blockIdx.x * 256 + threadIdx.x;   // float4 index
    float4 v = ((const float4*)uio)[idx];
    int c = (idx * 4) & 127;
    v.x = fmaxf(v.x * scale[c + 0] + shift[c + 0], 0.f);
    v.y = fmaxf(v.y * scale[c + 1] + shift[c + 1], 0.f);
    v.z = fmaxf(v.z * scale[c + 2] + shift[c + 2], 0.f);
    v.w = fmaxf(v.w * scale[c + 3] + shift[c + 3], 0.f);
    ((float4*)h)[idx] = v;
    ((float4*)uio)[idx] = make_float4(0.f, 0.f, 0.f, 0.f);
}

// -------- pool: per-graph mean & max over sorted batch (binary search) --------
__global__ __launch_bounds__(128) void k_pool(
    const float* __restrict__ h, const int* __restrict__ batch,
    float* __restrict__ pmean, float* __restrict__ pmax)
{
    const int g = blockIdx.x;
    const int tid = threadIdx.x;
    int lo = 0, hi = NN;
    while (lo < hi) { int mid = (lo + hi) >> 1; if (batch[mid] < g) lo = mid + 1; else hi = mid; }
    const int start = lo;
    hi = NN;
    while (lo < hi) { int mid = (lo + hi) >> 1; if (batch[mid] < g + 1) lo = mid + 1; else hi = mid; }
    const int end = lo;
    float s = 0.f, m = 0.f;
    for (int i = start; i < end; ++i) {
        float v = h[(size_t)i * HD + tid];
        s += v; m = fmaxf(m, v);
    }
    float cnt = (float)(end - start);
    pmean[g * HD + tid] = s / fmaxf(cnt, 1.f);
    pmax[g * HD + tid] = m;   // h >= 0 so 0-init matches reference's isfinite fixup
}

// ------------- classifier GEMM1: z1 = relu([mean||max] @ W + b) ---------------
__global__ __launch_bounds__(128) void k_cls1(
    const float* __restrict__ pmean, const float* __restrict__ pmax,
    const float* __restrict__ w, const float* __restrict__ b,
    float* __restrict__ z1)
{
    __shared__ float ps[16][H2];
    const int tid = threadIdx.x;
    const int row0 = blockIdx.x * 16;
    for (int i = tid; i < 16 * H2; i += 128) {
        int r = i >> 8, k = i & 255;
        ps[r][k] = (k < HD) ? pmean[(row0 + r) * HD + k]
                            : pmax[(row0 + r) * HD + k - HD];
    }
    __syncthreads();
    const int cp = tid & 63, rg = tid >> 6;
    float a0[8], a1[8];
    #pragma unroll
    for (int r = 0; r < 8; ++r) { a0[r] = 0.f; a1[r] = 0.f; }
    for (int kk = 0; kk < 64; ++kk) {
        float w00 = w[(kk * 4 + 0) * HD + cp];
        float w01 = w[(kk * 4 + 1) * HD + cp];
        float w02 = w[(kk * 4 + 2) * HD + cp];
        float w03 = w[(kk * 4 + 3) * HD + cp];
        float w10 = w[(kk * 4 + 0) * HD + cp + 64];
        float w11 = w[(kk * 4 + 1) * HD + cp + 64];
        float w12 = w[(kk * 4 + 2) * HD + cp + 64];
        float w13 = w[(kk * 4 + 3) * HD + cp + 64];
        #pragma unroll
        for (int r = 0; r < 8; ++r) {
            float4 z4 = *(const float4*)(&ps[rg * 8 + r][kk * 4]);
            a0[r] += z4.x * w00; a0[r] += z4.y * w01;
            a0[r] += z4.z * w02; a0[r] += z4.w * w03;
            a1[r] += z4.x * w10; a1[r] += z4.y * w11;
            a1[r] += z4.z * w12; a1[r] += z4.w * w13;
        }
    }
    const float bb0 = b[cp], bb1 = b[cp + 64];
    #pragma unroll
    for (int r = 0; r < 8; ++r) {
        int row = row0 + rg * 8 + r;
        z1[row * HD + cp]      = fmaxf(a0[r] + bb0, 0.f);
        z1[row * HD + cp + 64] = fmaxf(a1[r] + bb1, 0.f);
    }
}

// --------- column stats for classifier BN (small, atomics fine) --------------
__global__ __launch_bounds__(256) void k_colstats(
    const float* __restrict__ a, int nrows,
    float* __restrict__ ssum, float* __restrict__ ssumsq)
{
    const int tid = threadIdx.x;
    const int col = tid & 127;
    const int rsub = tid >> 7;
    const int r0 = blockIdx.x * 500;
    float s = 0.f, ss = 0.f;
    for (int i = rsub; i < 500; i += 2) {
        int r = r0 + i;
        if (r < nrows) {
            float v = a[r * HD + col];
            s += v; ss += v * v;
        }
    }
    atomicAdd(&ssum[col], s);
    atomicAdd(&ssumsq[col], ss);
}

__global__ void k_bnprep(float* __restrict__ ssum, float* __restrict__ ssumsq,
                         const float* __restrict__ g, const float* __restrict__ b,
                         float* __restrict__ scale, float* __restrict__ shift,
                         float invn)
{
    int c = threadIdx.x;
    if (c < HD) {
        float mean = ssum[c] * invn;
        float var = ssumsq[c] * invn - mean * mean;
        float sc = g[c] * rsqrtf(var + 1e-5f);
        scale[c] = sc;
        shift[c] = b[c] - mean * sc;
    }
}

// ---------------- classifier GEMM2: out = bn(z1) @ W2 + b2 --------------------
__global__ __launch_bounds__(256) void k_cls2(
    const float* __restrict__ z1, const float* __restrict__ scale,
    const float* __restrict__ shift, const float* __restrict__ w,
    const float* __restrict__ b, float* __restrict__ outp)
{
    __shared__ float zs[16][HD];
    const int tid = threadIdx.x;
    const int row0 = blockIdx.x * 16;
    for (int i = tid; i < 16 * HD; i += 256) {
        int r = i >> 7, k = i & 127;
        zs[r][k] = z1[(row0 + r) * HD + k] * scale[k] + shift[k];
    }
    __syncthreads();
    #pragma unroll
    for (int cpass = 0; cpass < 2; ++cpass) {
        int c = tid + cpass * 256;
        if (c < NC) {
            float acc[16];
            float bb = b[c];
            #pragma unroll
            for (int r = 0; r < 16; ++r) acc[r] = bb;
            for (int k = 0; k < HD; ++k) {
                float wv = w[k * NC + c];
                #pragma unroll
                for (int r = 0; r < 16; ++r) acc[r] += zs[r][k] * wv;
            }
            #pragma unroll
            for (int r = 0; r < 16; ++r) outp[(size_t)(row0 + r) * NC + c] = acc[r];
        }
    }
}

extern "C" void kernel_launch(void* const* d_in, const int* in_sizes, int n_in,
                              void* d_out, int out_size, void* d_ws, size_t ws_size,
                              hipStream_t stream)
{
    const float* x       = (const float*)d_in[0];
    const int*   ei      = (const int*)  d_in[1];
    const float* eattr   = (const float*)d_in[2];
    const int*   batch   = (const int*)  d_in[3];
    const float* node_w  = (const float*)d_in[4];
    const float* node_b  = (const float*)d_in[5];
    const float* edge_w  = (const float*)d_in[6];
    const float* edge_b  = (const float*)d_in[7];
    const float* conv_w1 = (const float*)d_in[8];
    const float* conv_b1 = (const float*)d_in[9];
    const float* bn1g    = (const float*)d_in[10];
    const float* bn1b    = (const float*)d_in[11];
    const float* conv_w2 = (const float*)d_in[12];
    const float* conv_b2 = (const float*)d_in[13];
    const float* bng     = (const float*)d_in[14];
    const float* bnb     = (const float*)d_in[15];
    const float* cw1     = (const float*)d_in[16];
    const float* cb1     = (const float*)d_in[17];
    const float* cbg     = (const float*)d_in[18];
    const float* cbb     = (const float*)d_in[19];
    const float* cw2     = (const float*)d_in[20];
    const float* cb2     = (const float*)d_in[21];
    float* out = (float*)d_out;
    float* ws  = (float*)d_ws;

    // ---- workspace layout (floats), total ~52.6M floats = 210 MB ----
    float* h   = ws;                          // 25,600,000
    float* agg = h + (size_t)NN * HD;         // 25,600,000 (aliased as u)
    float* z1  = agg + (size_t)NN * HD;       // 1,048,576
    float* st  = z1 + (size_t)NG * HD;        // stats + weight region
    float* u   = agg;

    float* uslotS  = st;            // 8192
    float* uslotSS = st + 8192;     // 8192
    float* clsS    = st + 16384;    // 128
    float* clsSS   = st + 16512;    // 128
    float* scale1  = st + 16640;    // 256
    float* shift1  = st + 16896;    // 256
    float* scale2  = st + 17152;    // 128
    float* shift2  = st + 17280;    // 128
    float* scalec  = st + 17408;    // 128
    float* shiftc  = st + 17536;    // 128
    float* M       = st + 17664;    // 16384
    float* colz    = st + 34048;    // 128
    short* wbfh    = (short*)(st + 34176);            // 262,144 shorts (131,072 f)
    short* wbfl    = (short*)(st + 34176 + 131072);   // 262,144 shorts

    // d_out scratch during the layer loop (out_size = 4,096,000 floats):
    //   Mpart [0 .. 3,932,160)  colzPart [3,932,160 .. 3,962,880)
    // pool/cls phase reuses d_out afterwards (temporally disjoint).
    float* Mpart    = out;
    float* colzPart = out + (size_t)ZBLK * 16384;
    float* pmean = out;
    float* pmax  = out + (size_t)NG * HD;

    // zero uslots + cls sums once (buffers re-poisoned to 0xAA before every call)
    k_zero<<<(16640 + 255) / 256, 256, 0, stream>>>(st, 16640);

    // preconvert all conv weights to MFMA-fragment-ordered bf16 hi/lo
    k_wprep<<<1024, 256, 0, stream>>>(conv_w1, conv_w2, wbfh, wbfl);

    k_node_encode<<<NN / 32, 256, 0, stream>>>(x, node_w, node_b, h, agg);

    for (int l = 0; l < 4; ++l) {
        k_msg_agg<<<NE / 32, 256, 0, stream>>>(h, ei, eattr, edge_w, edge_b, agg);
        k_zstats2<<<ZBLK, 256, 0, stream>>>(h, agg, Mpart, colzPart);
        k_mreduce<<<(16384 + HD + 255) / 256, 256, 0, stream>>>(Mpart, colzPart, M, colz);
        k_bnprep1<<<H2, 128, 0, stream>>>(M, colz,
                                          conv_w1 + (size_t)l * HD * H2,
                                          bn1g + (size_t)l * H2, bn1b + (size_t)l * H2,
                                          scale1, shift1);
        k_fused_mfma3<<<NN / 32, 128, 0, stream>>>(h, agg,
                                                   wbfh + (size_t)l * 65536,
                                                   wbfl + (size_t)l * 65536,
                                                   wbfh + (size_t)l * 65536 + 32768,
                                                   wbfl + (size_t)l * 65536 + 32768,
                                                   scale1, shift1,
                                                   conv_b2 + (size_t)l * HD, u);
        k_ustats<<<400, 256, 0, stream>>>(u, uslotS, uslotSS);
        k_bnprep2<<<1, 128, 0, stream>>>(uslotS, uslotSS,
                                         bng + (size_t)l * HD, bnb + (size_t)l * HD,
                                         scale2, shift2);
        k_norm<<<(NN * HD / 4) / 256, 256, 0, stream>>>(scale2, shift2, h, u);
    }

    k_pool<<<NG, 128, 0, stream>>>(h, batch, pmean, pmax);
    k_cls1<<<NG / 16, 128, 0, stream>>>(pmean, pmax, cw1, cb1, z1);
    k_colstats<<<17, 256, 0, stream>>>(z1, NG, clsS, clsSS);
    k_bnprep<<<1, 256, 0, stream>>>(clsS, clsSS, cbg, cbb, scalec, shiftc, 1.f / NG);
    k_cls2<<<NG / 16, 256, 0, stream>>>(z1, scalec, shiftc, cw2, cb2, out);
}

// Round 7
// 2659.870 us; speedup vs baseline: 2.4351x; 1.0148x over previous
//
#include <hip/hip_runtime.h>

#define NN 200000
#define NE 400000
#define NG 8192
#define HD 128
#define H2 256
#define ND 80
#define NC 500
#define ZBLK 240
#define NCHUNK 6250       // NN / 32 exactly

typedef short bf16x8 __attribute__((ext_vector_type(8)));
typedef short bf16x4 __attribute__((ext_vector_type(4)));
typedef float f32x4  __attribute__((ext_vector_type(4)));

static __device__ __forceinline__ short f2bf(float f) {
    unsigned u = __float_as_uint(f);
    unsigned r = (u + 0x7fffu + ((u >> 16) & 1u)) >> 16;
    return (short)r;
}
static __device__ __forceinline__ float bf2f(short s) {
    return __uint_as_float(((unsigned)(unsigned short)s) << 16);
}

// ------------------------------ zero helper ----------------------------------
__global__ void k_zero(float* p, int n) {
    int i = blockIdx.x * 256 + threadIdx.x;
    if (i < n) p[i] = 0.f;
}

// ---------------- node encoder: u = x @ node_w + node_b ; agg = 0 -------------
__global__ __launch_bounds__(256) void k_node_encode(
    const float* __restrict__ x, const float* __restrict__ w,
    const float* __restrict__ b, float* __restrict__ u, float* __restrict__ agg)
{
    __shared__ float ws[ND][HD];   // 40 KB
    __shared__ float xs[32][ND];   // 10 KB
    const int tid = threadIdx.x;
    for (int i = tid; i < ND * HD; i += 256) ws[i >> 7][i & 127] = w[i];
    const int row0 = blockIdx.x * 32;
    for (int i = tid; i < 32 * ND; i += 256) {
        int r = i / ND, c = i % ND;
        xs[r][c] = x[(size_t)(row0 + r) * ND + c];
    }
    __syncthreads();
    const int col = tid & 127, rs = tid >> 7;
    const float bias = b[col];
    for (int it = 0; it < 16; ++it) {
        int rl = it * 2 + rs;
        float acc = bias;
        #pragma unroll
        for (int k = 0; k < ND; ++k) acc += xs[rl][k] * ws[k][col];
        size_t gi = (size_t)(row0 + rl) * HD + col;
        u[gi] = acc;
        agg[gi] = 0.f;
    }
}

// -- message + aggregate: agg[dst] += relu(act(u[src]) + e_attr@ew + eb) ------
// act(v) = first ? v : relu(v*s2+sh2)
__global__ __launch_bounds__(256) void k_msg_agg(
    const float* __restrict__ u, const int* __restrict__ ei,
    const float* __restrict__ eattr, const float* __restrict__ ew,
    const float* __restrict__ eb, const float* __restrict__ s2,
    const float* __restrict__ sh2, float* __restrict__ agg, int first)
{
    __shared__ float ews[6][HD];
    __shared__ float ebs[HD], s2s[HD], sh2s[HD];
    const int tid = threadIdx.x;
    for (int i = tid; i < 6 * HD; i += 256) ews[i >> 7][i & 127] = ew[i];
    if (tid < HD) { ebs[tid] = eb[tid]; s2s[tid] = s2[tid]; sh2s[tid] = sh2[tid]; }
    __syncthreads();
    const int col = tid & 127, es = tid >> 7;
    const int e0 = blockIdx.x * 32;
    for (int it = 0; it < 16; ++it) {
        int e = e0 + it * 2 + es;
        int src = ei[e], dst = ei[NE + e];
        float a0 = eattr[e * 6 + 0], a1 = eattr[e * 6 + 1], a2 = eattr[e * 6 + 2];
        float a3 = eattr[e * 6 + 3], a4 = eattr[e * 6 + 4], a5 = eattr[e * 6 + 5];
        float hv = u[(size_t)src * HD + col];
        if (!first) hv = fmaxf(hv * s2s[col] + sh2s[col], 0.f);
        float m = hv + ebs[col]
                + a0 * ews[0][col] + a1 * ews[1][col] + a2 * ews[2][col]
                + a3 * ews[3][col] + a4 * ews[4][col] + a5 * ews[5][col];
        m = fmaxf(m, 0.f);
        atomicAdd(&agg[(size_t)dst * HD + col], m);
    }
}

// ---- Z-stats: partials of M = Z'Z and colsum(Z), Z = act(u) + agg ----------
__global__ __launch_bounds__(256) void k_zstats2(
    const float* __restrict__ u, const float* __restrict__ agg,
    const float* __restrict__ s2, const float* __restrict__ sh2,
    float* __restrict__ Mpart, float* __restrict__ colzPart, int first)
{
    __shared__ float zs[32][HD];      // 16 KB
    __shared__ float cred[8][HD];     // 4 KB
    const int tid = threadIdx.x;
    const int bid = blockIdx.x;
    const int i0 = (tid >> 5) * 16;
    const int j0 = (tid & 31) * 4;
    const int lrow = tid >> 5;
    const int lc4  = tid & 31;

    float4 sv = *(const float4*)(s2 + lc4 * 4);
    float4 shv = *(const float4*)(sh2 + lc4 * 4);

    float acc[16][4];
    #pragma unroll
    for (int a = 0; a < 16; ++a)
        #pragma unroll
        for (int b = 0; b < 4; ++b) acc[a][b] = 0.f;
    float4 csum = make_float4(0.f, 0.f, 0.f, 0.f);

    float4 pv[4];
    int chunk = bid;
    {
        const size_t r0 = (size_t)chunk * 32;
        #pragma unroll
        for (int i = 0; i < 4; ++i) {
            size_t gi = (r0 + lrow + i * 8) * HD + lc4 * 4;
            float4 hv = *(const float4*)(u + gi);
            float4 av = *(const float4*)(agg + gi);
            if (!first) {
                hv.x = fmaxf(hv.x * sv.x + shv.x, 0.f);
                hv.y = fmaxf(hv.y * sv.y + shv.y, 0.f);
                hv.z = fmaxf(hv.z * sv.z + shv.z, 0.f);
                hv.w = fmaxf(hv.w * sv.w + shv.w, 0.f);
            }
            pv[i] = make_float4(hv.x + av.x, hv.y + av.y, hv.z + av.z, hv.w + av.w);
        }
    }

    while (chunk < NCHUNK) {
        __syncthreads();
        #pragma unroll
        for (int i = 0; i < 4; ++i) {
            *(float4*)(&zs[lrow + i * 8][lc4 * 4]) = pv[i];
            csum.x += pv[i].x; csum.y += pv[i].y;
            csum.z += pv[i].z; csum.w += pv[i].w;
        }
        __syncthreads();
        int nxt = chunk + ZBLK;
        if (nxt < NCHUNK) {
            const size_t r0 = (size_t)nxt * 32;
            #pragma unroll
            for (int i = 0; i < 4; ++i) {
                size_t gi = (r0 + lrow + i * 8) * HD + lc4 * 4;
                float4 hv = *(const float4*)(u + gi);
                float4 av = *(const float4*)(agg + gi);
                if (!first) {
                    hv.x = fmaxf(hv.x * sv.x + shv.x, 0.f);
                    hv.y = fmaxf(hv.y * sv.y + shv.y, 0.f);
                    hv.z = fmaxf(hv.z * sv.z + shv.z, 0.f);
                    hv.w = fmaxf(hv.w * sv.w + shv.w, 0.f);
                }
                pv[i] = make_float4(hv.x + av.x, hv.y + av.y, hv.z + av.z, hv.w + av.w);
            }
        }
        #pragma unroll 8
        for (int r = 0; r < 32; ++r) {
            float4 zj  = *(const float4*)(&zs[r][j0]);
            float4 zi0 = *(const float4*)(&zs[r][i0]);
            float4 zi1 = *(const float4*)(&zs[r][i0 + 4]);
            float4 zi2 = *(const float4*)(&zs[r][i0 + 8]);
            float4 zi3 = *(const float4*)(&zs[r][i0 + 12]);
            float zi[16] = {zi0.x, zi0.y, zi0.z, zi0.w,
                            zi1.x, zi1.y, zi1.z, zi1.w,
                            zi2.x, zi2.y, zi2.z, zi2.w,
                            zi3.x, zi3.y, zi3.z, zi3.w};
            #pragma unroll
            for (int a = 0; a < 16; ++a) {
                acc[a][0] += zi[a] * zj.x;
                acc[a][1] += zi[a] * zj.y;
                acc[a][2] += zi[a] * zj.z;
                acc[a][3] += zi[a] * zj.w;
            }
        }
        chunk = nxt;
    }

    float* mp = Mpart + (size_t)bid * 16384;
    #pragma unroll
    for (int a = 0; a < 16; ++a)
        *(float4*)(mp + (i0 + a) * HD + j0) =
            make_float4(acc[a][0], acc[a][1], acc[a][2], acc[a][3]);

    *(float4*)(&cred[lrow][lc4 * 4]) = csum;
    __syncthreads();
    if (tid < HD) {
        float s = 0.f;
        #pragma unroll
        for (int k = 0; k < 8; ++k) s += cred[k][tid];
        colzPart[bid * HD + tid] = s;
    }
}

// ---- reduce partials ---------------------------------------------------------
__global__ __launch_bounds__(256) void k_mreduce(
    const float* __restrict__ Mpart, const float* __restrict__ colzPart,
    float* __restrict__ M, float* __restrict__ colz)
{
    int idx = blockIdx.x * 256 + threadIdx.x;
    if (idx < 16384) {
        float s = 0.f;
        for (int b = 0; b < ZBLK; ++b) s += Mpart[(size_t)b * 16384 + idx];
        M[idx] = s;
    } else if (idx < 16384 + HD) {
        int c = idx - 16384;
        float s = 0.f;
        for (int b = 0; b < ZBLK; ++b) s += colzPart[b * HD + c];
        colz[c] = s;
    }
}

// -- BN1 prep: var(Z@wc) = wc'M wc/N - (colz.wc/N)^2 ; conv bias b1 cancels ---
__global__ __launch_bounds__(128) void k_bnprep1(
    const float* __restrict__ M, const float* __restrict__ colz,
    const float* __restrict__ w1p,
    const float* __restrict__ g, const float* __restrict__ b,
    float* __restrict__ scale, float* __restrict__ shift)
{
    __shared__ float wcs[128];
    __shared__ float red[128];
    __shared__ float red2[128];
    const int c = blockIdx.x;
    const int j = threadIdx.x;
    float wc = w1p[j * H2 + c];
    wcs[j] = wc;
    __syncthreads();
    float inner = 0.f;
    for (int k = 0; k < 128; ++k) inner += M[j * HD + k] * wcs[k];
    red[j] = wc * inner;
    red2[j] = colz[j] * wc;
    __syncthreads();
    for (int s = 64; s > 0; s >>= 1) {
        if (j < s) { red[j] += red[j + s]; red2[j] += red2[j + s]; }
        __syncthreads();
    }
    if (j == 0) {
        const float invn = 1.f / NN;
        float q = red[0] * invn;
        float d = red2[0] * invn;
        float var = q - d * d;
        float sc = g[c] * rsqrtf(var + 1e-5f);
        scale[c] = sc;
        shift[c] = b[c] - d * sc;
    }
}

// -- W fragment preconversion: MFMA-operand-ordered bf16 hi/lo, all 4 layers --
__global__ __launch_bounds__(256) void k_wprep(
    const float* __restrict__ w1, const float* __restrict__ w2,
    short* __restrict__ wh, short* __restrict__ wlo)
{
    int id = blockIdx.x * 256 + threadIdx.x;
    int layer = id >> 16, r = id & 65535;
    float v;
    if (r < 32768) {
        int ft = r >> 11, kk = (r >> 9) & 3, l = (r >> 3) & 63, j = r & 7;
        int k = kk * 32 + (l >> 4) * 8 + j, c = ft * 16 + (l & 15);
        v = w1[(size_t)layer * HD * H2 + k * H2 + c];
    } else {
        int r2 = r - 32768;
        int ft = r2 >> 12, kk = (r2 >> 9) & 7, l = (r2 >> 3) & 63, j = r2 & 7;
        int k = kk * 32 + (l >> 4) * 8 + j, c = ft * 16 + (l & 15);
        v = w2[(size_t)layer * H2 * HD + k * HD + c];
    }
    short hi = f2bf(v);
    wh[id] = hi;
    wlo[id] = f2bf(v - bf2f(hi));
}

// ---- fused conv via 3-product bf16 MFMA, pipelined weight prefetch ----------
// Z = act(u)+agg; u_new = relu(bn1(Z@W1)) @ W2 + b2 (in place); agg zeroed.
__global__ __launch_bounds__(128, 2) void k_fused_mfma3(
    const float* uin, float* agg,
    const short* __restrict__ w1h, const short* __restrict__ w1l,
    const short* __restrict__ w2h, const short* __restrict__ w2l,
    const float* __restrict__ scale1, const float* __restrict__ shift1,
    const float* __restrict__ s2, const float* __restrict__ sh2,
    const float* __restrict__ b2p, float* uout, int first)
{
    __shared__ short ysh[32 * 256];   // 16 KB, XOR-swizzled 16B granules
    __shared__ short ysl[32 * 256];   // 16 KB
    __shared__ float sc1s[H2], sh1s[H2];
    const int tid = threadIdx.x;
    const int row0g = blockIdx.x * 32;
    for (int i = tid; i < H2; i += 128) { sc1s[i] = scale1[i]; sh1s[i] = shift1[i]; }

    const int l = tid & 63, w = tid >> 6;
    const int nq = l >> 4;
    const int node = w * 16 + (l & 15);
    const int nx = node & 7;
    const size_t zbase = (size_t)(row0g + node) * HD;

    // B-frags (Z^T) hi/lo from global: Z[node][kk*32+nq*8 .. +8]
    bf16x8 zh[4], zl[4];
    #pragma unroll
    for (int kk = 0; kk < 4; ++kk) {
        int c0 = kk * 32 + nq * 8;
        float4 u0 = *(const float4*)(uin + zbase + c0);
        float4 u1 = *(const float4*)(uin + zbase + c0 + 4);
        float4 a0 = *(const float4*)(agg + zbase + c0);
        float4 a1 = *(const float4*)(agg + zbase + c0 + 4);
        float z[8];
        if (first) {
            z[0]=u0.x+a0.x; z[1]=u0.y+a0.y; z[2]=u0.z+a0.z; z[3]=u0.w+a0.w;
            z[4]=u1.x+a1.x; z[5]=u1.y+a1.y; z[6]=u1.z+a1.z; z[7]=u1.w+a1.w;
        } else {
            float4 s0 = *(const float4*)(s2 + c0);
            float4 s1 = *(const float4*)(s2 + c0 + 4);
            float4 t0 = *(const float4*)(sh2 + c0);
            float4 t1 = *(const float4*)(sh2 + c0 + 4);
            z[0]=fmaxf(u0.x*s0.x+t0.x,0.f)+a0.x; z[1]=fmaxf(u0.y*s0.y+t0.y,0.f)+a0.y;
            z[2]=fmaxf(u0.z*s0.z+t0.z,0.f)+a0.z; z[3]=fmaxf(u0.w*s0.w+t0.w,0.f)+a0.w;
            z[4]=fmaxf(u1.x*s1.x+t1.x,0.f)+a1.x; z[5]=fmaxf(u1.y*s1.y+t1.y,0.f)+a1.y;
            z[6]=fmaxf(u1.z*s1.z+t1.z,0.f)+a1.z; z[7]=fmaxf(u1.w*s1.w+t1.w,0.f)+a1.w;
        }
        #pragma unroll
        for (int j = 0; j < 8; ++j) {
            short hi = f2bf(z[j]);
            zh[kk][j] = hi;
            zl[kk][j] = f2bf(z[j] - bf2f(hi));
        }
    }
    __syncthreads();   // sc1s/sh1s ready

    // phase A: pipelined over ft (double-buffered weight frags)
    bf16x8 pah[2][4], pal[2][4];
    #pragma unroll
    for (int kk = 0; kk < 4; ++kk) {
        int wi = (kk * 64 + l) * 8;
        pah[0][kk] = *(const bf16x8*)(w1h + wi);
        pal[0][kk] = *(const bf16x8*)(w1l + wi);
    }
    #pragma unroll
    for (int ft = 0; ft < 16; ++ft) {
        const int cur = ft & 1, nxt = cur ^ 1;
        if (ft < 15) {
            #pragma unroll
            for (int kk = 0; kk < 4; ++kk) {
                int wi = (((ft + 1) * 4 + kk) * 64 + l) * 8;
                pah[nxt][kk] = *(const bf16x8*)(w1h + wi);
                pal[nxt][kk] = *(const bf16x8*)(w1l + wi);
            }
        }
        f32x4 acc = {0.f, 0.f, 0.f, 0.f};
        #pragma unroll
        for (int kk = 0; kk < 4; ++kk) {
            acc = __builtin_amdgcn_mfma_f32_16x16x32_bf16(pah[cur][kk], zh[kk], acc, 0, 0, 0);
            acc = __builtin_amdgcn_mfma_f32_16x16x32_bf16(pah[cur][kk], zl[kk], acc, 0, 0, 0);
            acc = __builtin_amdgcn_mfma_f32_16x16x32_bf16(pal[cur][kk], zh[kk], acc, 0, 0, 0);
        }
        int f0 = ft * 16 + nq * 4;
        float4 scv = *(const float4*)(&sc1s[f0]);
        float4 shv = *(const float4*)(&sh1s[f0]);
        float y0 = fmaxf(acc[0] * scv.x + shv.x, 0.f);
        float y1 = fmaxf(acc[1] * scv.y + shv.y, 0.f);
        float y2 = fmaxf(acc[2] * scv.z + shv.z, 0.f);
        float y3 = fmaxf(acc[3] * scv.w + shv.w, 0.f);
        bf16x4 ph, pl;
        ph[0] = f2bf(y0); pl[0] = f2bf(y0 - bf2f(ph[0]));
        ph[1] = f2bf(y1); pl[1] = f2bf(y1 - bf2f(ph[1]));
        ph[2] = f2bf(y2); pl[2] = f2bf(y2 - bf2f(ph[2]));
        ph[3] = f2bf(y3); pl[3] = f2bf(y3 - bf2f(ph[3]));
        int off = node * 256 + (((f0 >> 3) ^ nx) * 8) + (nq & 1) * 4;
        *(bf16x4*)(&ysh[off]) = ph;
        *(bf16x4*)(&ysl[off]) = pl;
    }
    // no barrier: each wave reads only the ys rows it wrote

    // phase B: u^T = W2^T y^T, pipelined in 16 half-ft chunks of 4 kk
    bf16x8 ybh[8], ybl[8];
    #pragma unroll
    for (int kk = 0; kk < 8; ++kk) {
        int off = node * 256 + (((kk * 4 + nq) ^ nx) * 8);
        ybh[kk] = *(const bf16x8*)(&ysh[off]);
        ybl[kk] = *(const bf16x8*)(&ysl[off]);
    }
    bf16x8 qh[2][4], ql[2][4];
    #pragma unroll
    for (int kk = 0; kk < 4; ++kk) {
        int wi = (kk * 64 + l) * 8;
        qh[0][kk] = *(const bf16x8*)(w2h + wi);
        ql[0][kk] = *(const bf16x8*)(w2l + wi);
    }
    f32x4 acc = {0.f, 0.f, 0.f, 0.f};
    #pragma unroll
    for (int ch = 0; ch < 16; ++ch) {
        const int ft = ch >> 1, half = ch & 1, cur = ch & 1, nxt = cur ^ 1;
        if (ch < 15) {
            int ft2 = (ch + 1) >> 1, kb = ((ch + 1) & 1) * 4;
            #pragma unroll
            for (int kk = 0; kk < 4; ++kk) {
                int wi = ((ft2 * 8 + kb + kk) * 64 + l) * 8;
                qh[nxt][kk] = *(const bf16x8*)(w2h + wi);
                ql[nxt][kk] = *(const bf16x8*)(w2l + wi);
            }
        }
        if (half == 0) { acc[0] = 0.f; acc[1] = 0.f; acc[2] = 0.f; acc[3] = 0.f; }
        #pragma unroll
        for (int kk = 0; kk < 4; ++kk) {
            acc = __builtin_amdgcn_mfma_f32_16x16x32_bf16(qh[cur][kk], ybh[half*4+kk], acc, 0, 0, 0);
            acc = __builtin_amdgcn_mfma_f32_16x16x32_bf16(qh[cur][kk], ybl[half*4+kk], acc, 0, 0, 0);
            acc = __builtin_amdgcn_mfma_f32_16x16x32_bf16(ql[cur][kk], ybh[half*4+kk], acc, 0, 0, 0);
        }
        if (half == 1) {
            int f0 = ft * 16 + nq * 4;
            float4 bv = *(const float4*)(b2p + f0);
            float4 o = make_float4(acc[0] + bv.x, acc[1] + bv.y,
                                   acc[2] + bv.z, acc[3] + bv.w);
            *(float4*)(&uout[zbase + f0]) = o;
            *(float4*)(&agg[zbase + f0]) = make_float4(0.f, 0.f, 0.f, 0.f);
        }
    }
}

// --------- u column stats (separate pass; 64-slot atomics) -------------------
__global__ __launch_bounds__(256) void k_ustats(
    const float* __restrict__ u,
    float* __restrict__ uslotS, float* __restrict__ uslotSS)
{
    __shared__ float sS[2][HD], sQ[2][HD];
    const int tid = threadIdx.x;
    const int col = tid & 127, half = tid >> 7;
    size_t r0 = (size_t)blockIdx.x * 500 + half * 250;
    float s = 0.f, ss = 0.f;
    for (int i = 0; i < 250; ++i) {
        float v = u[(r0 + i) * HD + col];
        s += v; ss += v * v;
    }
    sS[half][col] = s; sQ[half][col] = ss;
    __syncthreads();
    if (tid < HD) {
        int slot = blockIdx.x & 63;
        atomicAdd(&uslotS[slot * HD + tid],  sS[0][tid] + sS[1][tid]);
        atomicAdd(&uslotSS[slot * HD + tid], sQ[0][tid] + sQ[1][tid]);
    }
}

// ------------- BN2 prep: reduce 64 slots, emit scale/shift, zero slots -------
__global__ __launch_bounds__(128) void k_bnprep2(
    float* __restrict__ uslotS, float* __restrict__ uslotSS,
    const float* __restrict__ g, const float* __restrict__ b,
    float* __restrict__ scale, float* __restrict__ shift)
{
    const int c = threadIdx.x;
    float s = 0.f, ss = 0.f;
    for (int k = 0; k < 64; ++k) {
        s  += uslotS[k * HD + c];
        ss += uslotSS[k * HD + c];
        uslotS[k * HD + c] = 0.f;
        uslotSS[k * HD + c] = 0.f;
    }
    const float invn = 1.f / NN;
    float mean = s * invn;
    float var = ss * invn - mean * mean;
    float sc = g[c] * rsqrtf(var + 1e-5f);
    scale[c] = sc;
    shift[c] = b[c] - mean * sc;
}

// ---- pool: per-graph mean & max of relu(u*s2+sh2) over sorted batch ---------
__global__ __launch_bounds__(128) void k_pool(
    const float* __restrict__ u, const int* __restrict__ batch,
    const float* __restrict__ s2, const float* __restrict__ sh2,
    float* __restrict__ pmean, float* __restrict__ pmax)
{
    const int g = blockIdx.x;
    const int tid = threadIdx.x;
    const float sc = s2[tid], sh = sh2[tid];
    int lo = 0, hi = NN;
    while (lo < hi) { int mid = (lo + hi) >> 1; if (batch[mid] < g) lo = mid + 1; else hi = mid; }
    const int start = lo;
    hi = NN;
    while (lo < hi) { int mid = (lo + hi) >> 1; if (batch[mid] < g + 1) lo = mid + 1; else hi = mid; }
    const int end = lo;
    float s = 0.f, m = 0.f;
    for (int i = start; i < end; ++i) {
        float v = fmaxf(u[(size_t)i * HD + tid] * sc + sh, 0.f);
        s += v; m = fmaxf(m, v);
    }
    float cnt = (float)(end - start);
    pmean[g * HD + tid] = s / fmaxf(cnt, 1.f);
    pmax[g * HD + tid] = m;
}

// ------------- classifier GEMM1: z1 = relu([mean||max] @ W + b) ---------------
__global__ __launch_bounds__(128) void k_cls1(
    const float* __restrict__ pmean, const float* __restrict__ pmax,
    const float* __restrict__ w, const float* __restrict__ b,
    float* __restrict__ z1)
{
    __shared__ float ps[16][H2];
    const int tid = threadIdx.x;
    const int row0 = blockIdx.x * 16;
    for (int i = tid; i < 16 * H2; i += 128) {
        int r = i >> 8, k = i & 255;
        ps[r][k] = (k < HD) ? pmean[(row0 + r) * HD + k]
                            : pmax[(row0 + r) * HD + k - HD];
    }
    __syncthreads();
    const int cp = tid & 63, rg = tid >> 6;
    float a0[8], a1[8];
    #pragma unroll
    for (int r = 0; r < 8; ++r) { a0[r] = 0.f; a1[r] = 0.f; }
    for (int kk = 0; kk < 64; ++kk) {
        float w00 = w[(kk * 4 + 0) * HD + cp];
        float w01 = w[(kk * 4 + 1) * HD + cp];
        float w02 = w[(kk * 4 + 2) * HD + cp];
        float w03 = w[(kk * 4 + 3) * HD + cp];
        float w10 = w[(kk * 4 + 0) * HD + cp + 64];
        float w11 = w[(kk * 4 + 1) * HD + cp + 64];
        float w12 = w[(kk * 4 + 2) * HD + cp + 64];
        float w13 = w[(kk * 4 + 3) * HD + cp + 64];
        #pragma unroll
        for (int r = 0; r < 8; ++r) {
            float4 z4 = *(const float4*)(&ps[rg * 8 + r][kk * 4]);
            a0[r] += z4.x * w00; a0[r] += z4.y * w01;
            a0[r] += z4.z * w02; a0[r] += z4.w * w03;
            a1[r] += z4.x * w10; a1[r] += z4.y * w11;
            a1[r] += z4.z * w12; a1[r] += z4.w * w13;
        }
    }
    const float bb0 = b[cp], bb1 = b[cp + 64];
    #pragma unroll
    for (int r = 0; r < 8; ++r) {
        int row = row0 + rg * 8 + r;
        z1[row * HD + cp]      = fmaxf(a0[r] + bb0, 0.f);
        z1[row * HD + cp + 64] = fmaxf(a1[r] + bb1, 0.f);
    }
}

// --------- column stats for classifier BN ------------------------------------
__global__ __launch_bounds__(256) void k_colstats(
    const float* __restrict__ a, int nrows,
    float* __restrict__ ssum, float* __restrict__ ssumsq)
{
    const int tid = threadIdx.x;
    const int col = tid & 127;
    const int rsub = tid >> 7;
    const int r0 = blockIdx.x * 500;
    float s = 0.f, ss = 0.f;
    for (int i = rsub; i < 500; i += 2) {
        int r = r0 + i;
        if (r < nrows) {
            float v = a[r * HD + col];
            s += v; ss += v * v;
        }
    }
    atomicAdd(&ssum[col], s);
    atomicAdd(&ssumsq[col], ss);
}

__global__ void k_bnprep(float* __restrict__ ssum, float* __restrict__ ssumsq,
                         const float* __restrict__ g, const float* __restrict__ b,
                         float* __restrict__ scale, float* __restrict__ shift,
                         float invn)
{
    int c = threadIdx.x;
    if (c < HD) {
        float mean = ssum[c] * invn;
        float var = ssumsq[c] * invn - mean * mean;
        float sc = g[c] * rsqrtf(var + 1e-5f);
        scale[c] = sc;
        shift[c] = b[c] - mean * sc;
    }
}

// ---------------- classifier GEMM2: out = bn(z1) @ W2 + b2 --------------------
__global__ __launch_bounds__(256) void k_cls2(
    const float* __restrict__ z1, const float* __restrict__ scale,
    const float* __restrict__ shift, const float* __restrict__ w,
    const float* __restrict__ b, float* __restrict__ outp)
{
    __shared__ float zs[16][HD];
    const int tid = threadIdx.x;
    const int row0 = blockIdx.x * 16;
    for (int i = tid; i < 16 * HD; i += 256) {
        int r = i >> 7, k = i & 127;
        zs[r][k] = z1[(row0 + r) * HD + k] * scale[k] + shift[k];
    }
    __syncthreads();
    #pragma unroll
    for (int cpass = 0; cpass < 2; ++cpass) {
        int c = tid + cpass * 256;
        if (c < NC) {
            float acc[16];
            float bb = b[c];
            #pragma unroll
            for (int r = 0; r < 16; ++r) acc[r] = bb;
            for (int k = 0; k < HD; ++k) {
                float wv = w[k * NC + c];
                #pragma unroll
                for (int r = 0; r < 16; ++r) acc[r] += zs[r][k] * wv;
            }
            #pragma unroll
            for (int r = 0; r < 16; ++r) outp[(size_t)(row0 + r) * NC + c] = acc[r];
        }
    }
}

extern "C" void kernel_launch(void* const* d_in, const int* in_sizes, int n_in,
                              void* d_out, int out_size, void* d_ws, size_t ws_size,
                              hipStream_t stream)
{
    const float* x       = (const float*)d_in[0];
    const int*   ei      = (const int*)  d_in[1];
    const float* eattr   = (const float*)d_in[2];
    const int*   batch   = (const int*)  d_in[3];
    const float* node_w  = (const float*)d_in[4];
    const float* node_b  = (const float*)d_in[5];
    const float* edge_w  = (const float*)d_in[6];
    const float* edge_b  = (const float*)d_in[7];
    const float* conv_w1 = (const float*)d_in[8];
    const float* conv_b1 = (const float*)d_in[9];
    const float* bn1g    = (const float*)d_in[10];
    const float* bn1b    = (const float*)d_in[11];
    const float* conv_w2 = (const float*)d_in[12];
    const float* conv_b2 = (const float*)d_in[13];
    const float* bng     = (const float*)d_in[14];
    const float* bnb     = (const float*)d_in[15];
    const float* cw1     = (const float*)d_in[16];
    const float* cb1     = (const float*)d_in[17];
    const float* cbg     = (const float*)d_in[18];
    const float* cbb     = (const float*)d_in[19];
    const float* cw2     = (const float*)d_in[20];
    const float* cb2     = (const float*)d_in[21];
    float* out = (float*)d_out;
    float* ws  = (float*)d_ws;

    // ---- workspace layout (floats), ~52.6M = 210 MB ----
    float* u   = ws;                          // 25,600,000
    float* agg = u + (size_t)NN * HD;         // 25,600,000
    float* z1  = agg + (size_t)NN * HD;       // 1,048,576
    float* st  = z1 + (size_t)NG * HD;        // stats + weights

    float* uslotS  = st;            // 8192
    float* uslotSS = st + 8192;     // 8192
    float* clsS    = st + 16384;    // 128
    float* clsSS   = st + 16512;    // 128
    float* scale1  = st + 16640;    // 256
    float* shift1  = st + 16896;    // 256
    float* scale2  = st + 17152;    // 128
    float* shift2  = st + 17280;    // 128
    float* scalec  = st + 17408;    // 128
    float* shiftc  = st + 17536;    // 128
    float* M       = st + 17664;    // 16384
    float* colz    = st + 34048;    // 128
    short* wbfh    = (short*)(st + 34176);            // 262,144 shorts
    short* wbfl    = (short*)(st + 34176 + 131072);   // 262,144 shorts

    // d_out scratch during the layer loop; reused by pool/cls afterwards.
    float* Mpart    = out;
    float* colzPart = out + (size_t)ZBLK * 16384;
    float* pmean = out;
    float* pmax  = out + (size_t)NG * HD;

    k_zero<<<(16640 + 255) / 256, 256, 0, stream>>>(st, 16640);
    k_wprep<<<1024, 256, 0, stream>>>(conv_w1, conv_w2, wbfh, wbfl);
    k_node_encode<<<NN / 32, 256, 0, stream>>>(x, node_w, node_b, u, agg);

    for (int l = 0; l < 4; ++l) {
        int first = (l == 0) ? 1 : 0;
        k_msg_agg<<<NE / 32, 256, 0, stream>>>(u, ei, eattr, edge_w, edge_b,
                                               scale2, shift2, agg, first);
        k_zstats2<<<ZBLK, 256, 0, stream>>>(u, agg, scale2, shift2,
                                            Mpart, colzPart, first);
        k_mreduce<<<(16384 + HD + 255) / 256, 256, 0, stream>>>(Mpart, colzPart, M, colz);
        k_bnprep1<<<H2, 128, 0, stream>>>(M, colz,
                                          conv_w1 + (size_t)l * HD * H2,
                                          bn1g + (size_t)l * H2, bn1b + (size_t)l * H2,
                                          scale1, shift1);
        k_fused_mfma3<<<NN / 32, 128, 0, stream>>>(u, agg,
                                                   wbfh + (size_t)l * 65536,
                                                   wbfl + (size_t)l * 65536,
                                                   wbfh + (size_t)l * 65536 + 32768,
                                                   wbfl + (size_t)l * 65536 + 32768,
                                                   scale1, shift1, scale2, shift2,
                                                   conv_b2 + (size_t)l * HD, u, first);
        k_ustats<<<400, 256, 0, stream>>>(u, uslotS, uslotSS);
        k_bnprep2<<<1, 128, 0, stream>>>(uslotS, uslotSS,
                                         bng + (size_t)l * HD, bnb + (size_t)l * HD,
                                         scale2, shift2);
    }

    k_pool<<<NG, 128, 0, stream>>>(u, batch, scale2, shift2, pmean, pmax);
    k_cls1<<<NG / 16, 128, 0, stream>>>(pmean, pmax, cw1, cb1, z1);
    k_colstats<<<17, 256, 0, stream>>>(z1, NG, clsS, clsSS);
    k_bnprep<<<1, 256, 0, stream>>>(clsS, clsSS, cbg, cbb, scalec, shiftc, 1.f / NG);
    k_cls2<<<NG / 16, 256, 0, stream>>>(z1, scalec, shiftc, cw2, cb2, out);
}